// Round 4
// baseline (1199.629 us; speedup 1.0000x reference)
//
#include <hip/hip_runtime.h>
#include <math.h>

typedef unsigned short ushort_t;
typedef __attribute__((ext_vector_type(8))) short bf16x8;
typedef __attribute__((ext_vector_type(4))) float f32x4;

// Problem constants
constexpr int CB = 16, CT = 100, CMCL = 100, CDIN = 200;
constexpr int CKC = 50, CHID = 128;
constexpr int XCH = 1330;
constexpr int NBT = CB * CT;       // 1600
constexpr int NNODE = 10002, NPATH = 20002;
constexpr int TRS = 114;           // tr_s ushort stride: 57 dwords, odd -> conflict-free
constexpr int HSTR = 136;          // lstm H row stride (ushorts): 272B = 16*17, b128-aligned

__device__ __forceinline__ float frcp(float v){ return __builtin_amdgcn_rcpf(v); }
__device__ __forceinline__ float fsigmoid(float v){ return frcp(1.f + __expf(-v)); }
__device__ __forceinline__ float ftanh_(float v){
  float e = __expf(-2.f*fabsf(v));
  return copysignf((1.f - e) * frcp(1.f + e), v);
}
__device__ __forceinline__ float wredsum(float v){
  #pragma unroll
  for (int off = 32; off; off >>= 1) v += __shfl_xor(v, off);
  return v;
}
__device__ __forceinline__ float wredmax(float v){
  #pragma unroll
  for (int off = 32; off; off >>= 1) v = fmaxf(v, __shfl_xor(v, off));
  return v;
}
__device__ __forceinline__ ushort_t f2b(float f){
  union { float f; unsigned u; } c{f};
  return (ushort_t)((c.u + 0x7FFFu + ((c.u >> 16) & 1u)) >> 16);
}
__device__ __forceinline__ float b2f(unsigned hbits){
  union { unsigned u; float f; } c{hbits << 16};
  return c.f;
}
__device__ __forceinline__ void b8f(const ushort_t* p, float* o){
  uint4 v = *reinterpret_cast<const uint4*>(p);
  o[0]=b2f(v.x & 0xFFFFu); o[1]=b2f(v.x >> 16);
  o[2]=b2f(v.y & 0xFFFFu); o[3]=b2f(v.y >> 16);
  o[4]=b2f(v.z & 0xFFFFu); o[5]=b2f(v.z >> 16);
  o[6]=b2f(v.w & 0xFFFFu); o[7]=b2f(v.w >> 16);
}

// ---------------- MFMA bf16 GEMM: C = A(MxK,f32) * B(NxK,f32)^T (+bias), out f32 or bf16 ----------------
template<bool OUT_BF16>
__global__ __launch_bounds__(256) void gemm_mfma(
    const float* __restrict__ A, int lda,
    const float* __restrict__ B, int ldb,
    void* __restrict__ Cv, int ldc,
    int M, int N, int Npad, int K,
    const float* __restrict__ bias1, const float* __restrict__ bias2)
{
  __shared__ ushort_t As[128][40];
  __shared__ ushort_t Bs[64][40];
  const int tid = threadIdx.x;
  const int lane = tid & 63, wid = tid >> 6;
  const int wm = wid & 1, wn = wid >> 1;
  const int bm = blockIdx.x * 128, bn = blockIdx.y * 64;
  const int lr = lane & 15, lk = (lane >> 4) * 8;

  f32x4 acc[4][2];
  #pragma unroll
  for (int i = 0; i < 4; ++i)
    #pragma unroll
    for (int j = 0; j < 2; ++j) acc[i][j] = f32x4{0.f,0.f,0.f,0.f};

  const int arow = tid >> 1, akh = (tid & 1) * 16;
  const int brow = tid >> 2, bkh = (tid & 3) * 8;
  const int nk = (K + 31) / 32;
  for (int ks = 0; ks < nk; ++ks) {
    const int k0 = ks * 32;
    {
      int gm = bm + arow;
      const float* ap = A + (long)gm * lda + k0 + akh;
      #pragma unroll
      for (int j = 0; j < 8; ++j) {
        int kk = k0 + akh + 2*j;
        float2 v = make_float2(0.f, 0.f);
        if (gm < M && kk + 2 <= K) v = *reinterpret_cast<const float2*>(ap + 2*j);
        As[arow][akh + 2*j]     = f2b(v.x);
        As[arow][akh + 2*j + 1] = f2b(v.y);
      }
    }
    {
      int gn = bn + brow;
      const float* bp = B + (long)gn * ldb + k0 + bkh;
      #pragma unroll
      for (int j = 0; j < 4; ++j) {
        int kk = k0 + bkh + 2*j;
        float2 v = make_float2(0.f, 0.f);
        if (gn < N && kk + 2 <= K) v = *reinterpret_cast<const float2*>(bp + 2*j);
        Bs[brow][bkh + 2*j]     = f2b(v.x);
        Bs[brow][bkh + 2*j + 1] = f2b(v.y);
      }
    }
    __syncthreads();
    bf16x8 af[4], bf[2];
    #pragma unroll
    for (int i = 0; i < 4; ++i)
      af[i] = *reinterpret_cast<const bf16x8*>(&As[wm*64 + i*16 + lr][lk]);
    #pragma unroll
    for (int j = 0; j < 2; ++j)
      bf[j] = *reinterpret_cast<const bf16x8*>(&Bs[wn*32 + j*16 + lr][lk]);
    #pragma unroll
    for (int i = 0; i < 4; ++i)
      #pragma unroll
      for (int j = 0; j < 2; ++j)
        acc[i][j] = __builtin_amdgcn_mfma_f32_16x16x32_bf16(af[i], bf[j], acc[i][j], 0, 0, 0);
    __syncthreads();
  }
  #pragma unroll
  for (int i = 0; i < 4; ++i) {
    #pragma unroll
    for (int j = 0; j < 2; ++j) {
      #pragma unroll
      for (int r = 0; r < 4; ++r) {
        int gr = bm + wm*64 + i*16 + (lane >> 4)*4 + r;
        int gc = bn + wn*32 + j*16 + lr;
        if (gr < M && gc < Npad) {
          float v = acc[i][j][r];
          if (gc < N) {
            if (bias1) v += bias1[gc];
            if (bias2) v += bias2[gc];
          } else v = 0.f;
          if (OUT_BF16) ((ushort_t*)Cv)[(long)gr * ldc + gc] = f2b(v);
          else          ((float*)Cv)[(long)gr * ldc + gc]  = v;
        }
      }
    }
  }
}

// ---------------- pack embeddings: cols 0..111 of a `stride`-wide bf16 row ----------------
__global__ void pack_emb(const float* __restrict__ emb, ushort_t* __restrict__ V, int rows, int stride)
{
  int i = blockIdx.x * 256 + threadIdx.x;
  int r = i / 112, c = i % 112;
  if (r < rows) V[(long)r*stride + c] = (c < 100) ? f2b(emb[(long)r*100 + c]) : (ushort_t)0;
}
__global__ void pack_wattn(const float* __restrict__ Wattn, ushort_t* __restrict__ wab)
{
  int i = blockIdx.x * 256 + threadIdx.x;
  if (i < 512) wab[i] = (i < 500) ? f2b(Wattn[i]) : (ushort_t)0;
}

// ---------------- cw: per (b,t), all m: Wattn . tanh(T0A[a]+T0C[c]+TPP[p]+R) ----------------
__global__ __launch_bounds__(256) void cw2_kernel(
    const float* __restrict__ x, const ushort_t* __restrict__ T0A,
    const ushort_t* __restrict__ T0C, const ushort_t* __restrict__ TPP,
    const ushort_t* __restrict__ RB, const ushort_t* __restrict__ WAB,
    const float* __restrict__ battn, float* __restrict__ cwT)
{
  int bt = blockIdx.x, b = bt / CT, t = bt % CT;
  int tid = threadIdx.x, w = tid >> 6, lane = tid & 63;
  __shared__ int idx_s[300];
  for (int i = tid; i < 300; i += 256) idx_s[i] = (int)x[(long)bt*XCH + 200 + i];
  float rseg[8], wseg[8];
  b8f(RB + (long)bt*512 + lane*8, rseg);
  b8f(WAB + lane*8, wseg);
  __syncthreads();
  float bat = battn[0];

  uint4 A0, C0, P0, A1, C1, P1;
  auto issue = [&](int m, uint4& A, uint4& C, uint4& P){
    if (m < CMCL) {
      int ai = idx_s[3*m], pi = idx_s[3*m+1], ci = idx_s[3*m+2];
      A = *reinterpret_cast<const uint4*>(T0A + (long)ai*512 + lane*8);
      C = *reinterpret_cast<const uint4*>(T0C + (long)ci*512 + lane*8);
      P = *reinterpret_cast<const uint4*>(TPP + (long)pi*512 + lane*8);
    }
  };
  auto proc = [&](int m, const uint4& A, const uint4& C, const uint4& P){
    if (m >= CMCL) return;
    const unsigned ua[4] = {A.x, A.y, A.z, A.w};
    const unsigned uc[4] = {C.x, C.y, C.z, C.w};
    const unsigned up[4] = {P.x, P.y, P.z, P.w};
    float acc = 0.f;
    #pragma unroll
    for (int jj = 0; jj < 4; ++jj) {
      float lo = b2f(ua[jj] & 0xffffu) + b2f(uc[jj] & 0xffffu) + b2f(up[jj] & 0xffffu) + rseg[2*jj];
      float hi = b2f(ua[jj] >> 16)     + b2f(uc[jj] >> 16)     + b2f(up[jj] >> 16)     + rseg[2*jj+1];
      acc = fmaf(ftanh_(lo), wseg[2*jj], acc);
      acc = fmaf(ftanh_(hi), wseg[2*jj+1], acc);
    }
    acc = wredsum(acc);
    if (lane == 0) cwT[((long)b*CMCL + m)*CT + t] = acc + bat;
  };

  issue(w, A0, C0, P0);
  for (int it = 0; it < 25; it += 2) {
    int m0 = w + it*4;
    issue(m0 + 4, A1, C1, P1);
    proc(m0, A0, C0, P0);
    issue(m0 + 8, A0, C0, P0);
    proc(m0 + 4, A1, C1, P1);
  }
}

// ---------------- aw: softmax over t for each (b,m) ----------------
__global__ void aw_kernel(const float* __restrict__ cwT, float* __restrict__ awT)
{
  int bm = blockIdx.x; int lane = threadIdx.x;   // 64 threads
  const float* row = cwT + (long)bm * CT;
  bool h1 = lane < (CT - 64);
  float v0 = row[lane];
  float v1 = h1 ? row[64 + lane] : -3.0e38f;
  float mx = wredmax(fmaxf(v0, v1));
  float e0 = __expf(v0 - mx);
  float e1 = h1 ? __expf(v1 - mx) : 0.f;
  float s = wredsum(e0 + e1);
  float inv = frcp(s);
  awT[(long)bm*CT + lane] = e0 * inv;
  if (h1) awT[(long)bm*CT + 64 + lane] = e1 * inv;
}

// ---------------- fused: na + trans(LDS bf16) + kc-attention -> rnn[0:850] ----------------
__global__ __launch_bounds__(256) void fuse2_kernel(
    const float* __restrict__ x,
    const ushort_t* __restrict__ VAC, const ushort_t* __restrict__ VP,
    const ushort_t* __restrict__ RWB, const float* __restrict__ awT,
    const float* __restrict__ kc_emb, float* __restrict__ rnn)
{
  int bt = blockIdx.x, b = bt / CT, t = bt % CT;
  int tid = threadIdx.x, w = tid >> 6, lane = tid & 63;
  int sub = lane >> 5, li = lane & 31;

  __shared__ ushort_t tr_s[100*TRS];   // 22800 B
  __shared__ float nacc[4][344];
  __shared__ float ia_red[4][104];
  __shared__ float aw_s[100];
  __shared__ int   idx_s[300];
  __shared__ float kcl[CKC];
  __shared__ int   act_k[CKC];
  __shared__ int   nact_s;
  __shared__ float kcn_s, awsum_s;

  for (int i = tid; i < 300; i += 256) idx_s[i] = (int)x[(long)bt*XCH + 200 + i];
  if (tid < 100) aw_s[tid] = awT[((long)b*CMCL + tid)*CT + t];
  if (tid < CKC) kcl[tid] = x[(long)bt*XCH + 1280 + tid];
  __syncthreads();
  if (tid == 0) {
    float kcn = 0.f; int na = 0;
    for (int k = 0; k < CKC; ++k) { float v = kcl[k]; kcn += v; if (v != 0.f) act_k[na++] = k; }
    nact_s = na; kcn_s = (kcn == 0.f) ? 1.f : kcn;
    float s = 0.f;
    for (int m = 0; m < CMCL; ++m) s += aw_s[m];
    awsum_s = s;
  }
  float rwseg[8];
  if (li >= 14 && li < 28) b8f(RWB + (long)bt*112 + (li-14)*8, rwseg);
  __syncthreads();

  // ---- gather phase: 8 m per iteration (4 waves x 2 sub-halves), 2-stage pipeline ----
  float na_a[8] = {}, na_c[8] = {}, na_p[8] = {};
  const bool gv = (li < 28);
  uint4 A0, C0, P0, A1, C1, P1;
  auto g_issue = [&](int m, uint4& A, uint4& C, uint4& P){
    if (m < CMCL && gv) {
      int ai = idx_s[3*m], pi = idx_s[3*m+1], ci = idx_s[3*m+2];
      int eo = li*8, uo = (li-14)*8;
      A = *reinterpret_cast<const uint4*>(VAC + (long)ai*336 + ((li<14) ? eo : 112 + uo));
      C = *reinterpret_cast<const uint4*>(VAC + (long)ci*336 + ((li<14) ? eo : 224 + uo));
      P = *reinterpret_cast<const uint4*>(VP  + (long)pi*224 + eo);
    }
  };
  auto g_proc = [&](int m, const uint4& A, const uint4& C, const uint4& P){
    if (m >= CMCL || !gv) return;
    const unsigned ua[4] = {A.x, A.y, A.z, A.w};
    const unsigned uc[4] = {C.x, C.y, C.z, C.w};
    const unsigned up[4] = {P.x, P.y, P.z, P.w};
    if (li < 14) {
      float awm = aw_s[m];
      #pragma unroll
      for (int jj = 0; jj < 4; ++jj) {
        na_a[2*jj]   = fmaf(awm, b2f(ua[jj] & 0xffffu), na_a[2*jj]);
        na_a[2*jj+1] = fmaf(awm, b2f(ua[jj] >> 16),     na_a[2*jj+1]);
        na_c[2*jj]   = fmaf(awm, b2f(uc[jj] & 0xffffu), na_c[2*jj]);
        na_c[2*jj+1] = fmaf(awm, b2f(uc[jj] >> 16),     na_c[2*jj+1]);
        na_p[2*jj]   = fmaf(awm, b2f(up[jj] & 0xffffu), na_p[2*jj]);
        na_p[2*jj+1] = fmaf(awm, b2f(up[jj] >> 16),     na_p[2*jj+1]);
      }
    } else {
      unsigned* d32 = reinterpret_cast<unsigned*>(&tr_s[m*TRS + (li-14)*8]);
      #pragma unroll
      for (int jj = 0; jj < 4; ++jj) {
        float lo = b2f(ua[jj] & 0xffffu) + b2f(uc[jj] & 0xffffu) + b2f(up[jj] & 0xffffu) + rwseg[2*jj];
        float hi = b2f(ua[jj] >> 16)     + b2f(uc[jj] >> 16)     + b2f(up[jj] >> 16)     + rwseg[2*jj+1];
        d32[jj] = (unsigned)f2b(lo) | ((unsigned)f2b(hi) << 16);
      }
    }
  };
  const int mb = w*2 + sub;
  g_issue(mb, A0, C0, P0);
  for (int it = 0; it < 13; it += 2) {
    g_issue((it+1)*8 + mb, A1, C1, P1);
    g_proc(it*8 + mb, A0, C0, P0);
    g_issue((it+2)*8 + mb, A0, C0, P0);
    g_proc((it+1)*8 + mb, A1, C1, P1);
  }
  // combine sub-halves of na
  #pragma unroll
  for (int j = 0; j < 8; ++j) {
    na_a[j] += __shfl_xor(na_a[j], 32);
    na_c[j] += __shfl_xor(na_c[j], 32);
    na_p[j] += __shfl_xor(na_p[j], 32);
  }
  if (lane < 14) {
    #pragma unroll
    for (int j = 0; j < 8; ++j) {
      nacc[w][      lane*8 + j] = na_a[j];
      nacc[w][112 + lane*8 + j] = na_c[j];
      nacc[w][224 + lane*8 + j] = na_p[j];
    }
  }
  __syncthreads();

  // ---- na epilogue + passthroughs ----
  for (int q = tid; q < 336; q += 256) {
    float v = nacc[0][q] + nacc[1][q] + nacc[2][q] + nacc[3][q];
    int seg = q / 112, col = q % 112;
    if (col < 100) rnn[(long)bt*950 + 350 + seg*100 + col] = v;
  }
  for (int q = tid; q < CDIN; q += 256) {
    float xv = x[(long)bt*XCH + q];
    rnn[(long)bt*950 + 50 + q] = xv;
    rnn[(long)bt*950 + 650 + q] = awsum_s * xv;
  }
  if (tid < CKC) rnn[(long)bt*950 + tid] = kcl[tid];

  // ---- kc attention (dword-pair LDS reads, conflict-free stride) ----
  float ia0 = 0.f, ia1 = 0.f;
  const bool vrow1 = lane < 36;   // owns row 64+lane
  const bool vpv   = lane < 50;   // owns dims 2*lane, 2*lane+1
  const int nact = nact_s;
  const unsigned* tr32_0 = reinterpret_cast<const unsigned*>(&tr_s[lane*TRS]);
  const unsigned* tr32_1 = reinterpret_cast<const unsigned*>(&tr_s[(64+lane)*TRS]);
  const unsigned* tr32   = reinterpret_cast<const unsigned*>(tr_s);
  for (int ki = w; ki < nact; ki += 4) {
    int k = act_k[ki];
    float kck = kcl[k];
    const float* ke = kc_emb + (long)k*100;
    float s0 = 0.f, s1 = 0.f;
    #pragma unroll 5
    for (int dh = 0; dh < 50; ++dh) {
      float k0 = ke[2*dh], k1 = ke[2*dh+1];
      unsigned u0 = tr32_0[dh];
      s0 = fmaf(k0, b2f(u0 & 0xffffu), s0);
      s0 = fmaf(k1, b2f(u0 >> 16), s0);
      if (vrow1) {
        unsigned u1 = tr32_1[dh];
        s1 = fmaf(k0, b2f(u1 & 0xffffu), s1);
        s1 = fmaf(k1, b2f(u1 >> 16), s1);
      }
    }
    s0 *= kck; s1 *= kck;
    float mx = wredmax(fmaxf(s0, vrow1 ? s1 : -3.0e38f));
    float p0e = __expf(s0 - mx);
    float p1e = vrow1 ? __expf(s1 - mx) : 0.f;
    float sm = wredsum(p0e + p1e);
    float inv = kck * frcp(sm);
    p0e *= inv; p1e *= inv;
    #pragma unroll 4
    for (int m = 0; m < CMCL; ++m) {
      float pm = (m < 64) ? __shfl(p0e, m) : __shfl(p1e, m - 64);
      if (vpv) {
        unsigned u = tr32[m*57 + lane];
        ia0 = fmaf(pm, b2f(u & 0xffffu), ia0);
        ia1 = fmaf(pm, b2f(u >> 16), ia1);
      }
    }
  }
  if (vpv) { ia_red[w][2*lane] = ia0; ia_red[w][2*lane+1] = ia1; }
  __syncthreads();
  if (tid < 100) {
    float v = (ia_red[0][tid] + ia_red[1][tid] + ia_red[2][tid] + ia_red[3][tid]) * frcp(kcn_s);
    rnn[(long)bt*950 + 250 + tid] = v;
  }
}

// ---------------- LSTM via MFMA: grid=2 blocks x 8 batches, Whh frags in VGPRs ----------------
// Wave w owns h indices [16w,16w+16) for all 4 gate types (N-tiles w, w+8, w+16, w+24).
__global__ __launch_bounds__(512) void lstm_mfma_kernel(
    const ushort_t* __restrict__ preb,   // (NBT,512) bf16 pre-activations
    const float* __restrict__ Whh,       // (512,128) f32
    float* __restrict__ lstm_out)        // (B,T,128) f32
{
  constexpr int NB = 8;                  // batches per block
  const int b0 = blockIdx.x * NB;
  const int tid = threadIdx.x, lane = tid & 63, w = tid >> 6;
  const int lr = lane & 15, lkq = lane >> 4;       // k-quarter / row-quarter
  __shared__ ushort_t H[2][16 * HSTR];

  for (int i = tid; i < 2*16*HSTR; i += 512) H[0][i] = 0;  // zero both buffers (flat)

  // Whh B-frags in registers: tile q covers gates n0 = q*128 + w*16 .. +16
  bf16x8 bw[4][4];
  #pragma unroll
  for (int q = 0; q < 4; ++q) {
    const float* wp = Whh + (long)(q*128 + w*16 + lr) * 128;
    #pragma unroll
    for (int kk = 0; kk < 4; ++kk) {
      short s[8];
      #pragma unroll
      for (int j = 0; j < 8; ++j) s[j] = (short)f2b(wp[kk*32 + lkq*8 + j]);
      bw[q][kk] = bf16x8{s[0],s[1],s[2],s[3],s[4],s[5],s[6],s[7]};
    }
  }

  f32x4 c = {0.f,0.f,0.f,0.f};
  float pcur[4][4], pnxt[4][4];
  auto loadpre = [&](int t, float p[4][4]){
    #pragma unroll
    for (int q = 0; q < 4; ++q)
      #pragma unroll
      for (int r = 0; r < 4; ++r) {
        int row = lkq*4 + r;
        p[q][r] = (row < NB) ? b2f(preb[((long)(b0+row)*CT + t)*512 + q*128 + w*16 + lr]) : 0.f;
      }
  };
  loadpre(0, pcur);
  __syncthreads();

  int pb = 0;
  for (int t = 0; t < CT; ++t) {
    if (t + 1 < CT) loadpre(t + 1, pnxt);
    // A-frags: H[pb] rows = batch-local, k = hidden
    bf16x8 a[4];
    #pragma unroll
    for (int kk = 0; kk < 4; ++kk)
      a[kk] = *reinterpret_cast<const bf16x8*>(&H[pb][lr*HSTR + kk*32 + lkq*8]);
    f32x4 acc0 = f32x4{pcur[0][0], pcur[0][1], pcur[0][2], pcur[0][3]};
    f32x4 acc1 = f32x4{pcur[1][0], pcur[1][1], pcur[1][2], pcur[1][3]};
    f32x4 acc2 = f32x4{pcur[2][0], pcur[2][1], pcur[2][2], pcur[2][3]};
    f32x4 acc3 = f32x4{pcur[3][0], pcur[3][1], pcur[3][2], pcur[3][3]};
    #pragma unroll
    for (int kk = 0; kk < 4; ++kk) {
      acc0 = __builtin_amdgcn_mfma_f32_16x16x32_bf16(a[kk], bw[0][kk], acc0, 0,0,0);
      acc1 = __builtin_amdgcn_mfma_f32_16x16x32_bf16(a[kk], bw[1][kk], acc1, 0,0,0);
      acc2 = __builtin_amdgcn_mfma_f32_16x16x32_bf16(a[kk], bw[2][kk], acc2, 0,0,0);
      acc3 = __builtin_amdgcn_mfma_f32_16x16x32_bf16(a[kk], bw[3][kk], acc3, 0,0,0);
    }
    // activations: lane owns (rows lkq*4+r, h = w*16+lr)
    f32x4 hv;
    #pragma unroll
    for (int r = 0; r < 4; ++r) {
      float ig = fsigmoid(acc0[r]);
      float fg = fsigmoid(acc1[r]);
      float gg = ftanh_(acc2[r]);
      float og = fsigmoid(acc3[r]);
      c[r] = fg*c[r] + ig*gg;
      hv[r] = og * ftanh_(c[r]);
    }
    #pragma unroll
    for (int r = 0; r < 4; ++r) {
      int row = lkq*4 + r;
      H[pb^1][row*HSTR + w*16 + lr] = f2b(hv[r]);
      if (row < NB) lstm_out[((long)(b0+row)*CT + t)*128 + w*16 + lr] = hv[r];
    }
    __syncthreads();
    pb ^= 1;
    #pragma unroll
    for (int q = 0; q < 4; ++q)
      #pragma unroll
      for (int r = 0; r < 4; ++r) pcur[q][r] = pnxt[q][r];
  }
}

// ---------------- w: dot over [bert_vec, kc, ia] segments of rnn ----------------
__global__ void w_kernel(const float* __restrict__ rnn, const float* __restrict__ Wt,
                         const float* __restrict__ bt0, float* __restrict__ wbuf)
{
  int bt = blockIdx.x; int lane = threadIdx.x; // 64 threads
  float acc = 0.f;
  for (int i = lane; i < 250; i += 64) {
    float f;
    if (i < 100)      f = rnn[(long)bt*950 + 850 + i];
    else if (i < 150) f = rnn[(long)bt*950 + (i - 100)];
    else              f = rnn[(long)bt*950 + 250 + (i - 150)];
    acc = fmaf(Wt[i], f, acc);
  }
  acc = wredsum(acc);
  if (lane == 0) wbuf[bt] = acc + bt0[0];
}

__global__ void transpose_wfc(const float* __restrict__ Wfc, float* __restrict__ WfcT)
{
  int i = blockIdx.x*256 + threadIdx.x;
  if (i < 100*378) { int o = i / 378, q = i % 378; WfcT[q*100 + o] = Wfc[i]; }
}

// ---------------- final: causal attention + attended + FC + sigmoid ----------------
__global__ __launch_bounds__(256) void final_kernel(
    const float* __restrict__ x, const float* __restrict__ wbuf,
    const float* __restrict__ lstm_out, const float* __restrict__ WfcT,
    const float* __restrict__ bfc, float* __restrict__ out)
{
  int bt = blockIdx.x; int b = bt / CT, i = bt % CT;
  int tid = threadIdx.x;
  __shared__ float p_s[CT];
  __shared__ float feat_s[384];
  if (tid < 64) {
    bool h1 = (64 + tid) < CT;
    float v0 = (tid <= i) ? wbuf[(long)b*CT + tid] : -3.0e38f;
    float v1 = (h1 && (64 + tid) <= i) ? wbuf[(long)b*CT + 64 + tid] : -3.0e38f;
    float mx = wredmax(fmaxf(v0, v1));
    float e0 = (tid <= i) ? __expf(v0 - mx) : 0.f;
    float e1 = (h1 && (64 + tid) <= i) ? __expf(v1 - mx) : 0.f;
    float s = wredsum(e0 + e1);
    float inv = frcp(s);
    p_s[tid] = e0 * inv;
    if (h1) p_s[64 + tid] = e1 * inv;
  }
  __syncthreads();
  if (tid < CHID) {
    float cur = 0.f;
    #pragma unroll 4
    for (int j = 0; j <= i; ++j) cur = fmaf(p_s[j], lstm_out[((long)b*CT + j)*CHID + tid], cur);
    float l = lstm_out[((long)b*CT + i)*CHID + tid];
    float att;
    if (i == 0) att = l;
    else { att = 0.5f * l; if (i <= CT - 2) att = fmaf(0.5f, cur, att); }
    feat_s[250 + tid] = att;
  }
  for (int q = tid; q < 250; q += 256)
    feat_s[q] = (q < 200) ? x[(long)bt*XCH + q] : x[(long)bt*XCH + 1280 + (q - 200)];
  __syncthreads();
  if (tid < 100) {
    float acc = bfc[tid];
    #pragma unroll 4
    for (int q = 0; q < 378; ++q) acc = fmaf(WfcT[q*100 + tid], feat_s[q], acc);
    out[(long)bt*100 + tid] = fsigmoid(acc);
  }
}

extern "C" void kernel_launch(void* const* d_in, const int* in_sizes, int n_in,
                              void* d_out, int out_size, void* d_ws, size_t ws_size,
                              hipStream_t stream) {
  (void)in_sizes; (void)n_in; (void)out_size; (void)ws_size;
  const float* x        = (const float*)d_in[0];
  const float* node_emb = (const float*)d_in[1];
  const float* path_emb = (const float*)d_in[2];
  const float* Wb       = (const float*)d_in[3];
  const float* bb       = (const float*)d_in[4];
  const float* Wna      = (const float*)d_in[5];
  const float* bna      = (const float*)d_in[6];
  const float* Wia      = (const float*)d_in[7];
  const float* bia      = (const float*)d_in[8];
  const float* Wattn    = (const float*)d_in[9];
  const float* battn    = (const float*)d_in[10];
  const float* kc_emb   = (const float*)d_in[11];
  const float* Wt       = (const float*)d_in[12];
  const float* bt0      = (const float*)d_in[13];
  const float* Wih      = (const float*)d_in[14];
  const float* Whh      = (const float*)d_in[15];
  const float* bih      = (const float*)d_in[16];
  const float* bhh      = (const float*)d_in[17];
  const float* Wfc      = (const float*)d_in[18];
  const float* bfc      = (const float*)d_in[19];
  float* out = (float*)d_out;

  char* cur = (char*)d_ws;
  auto alloc = [&](size_t bytes)->char* {
    char* p = cur; cur += (bytes + 255) & ~(size_t)255; return p;
  };
  ushort_t* T0A = (ushort_t*)alloc((size_t)NNODE*512*2);
  ushort_t* T0C = (ushort_t*)alloc((size_t)NNODE*512*2);
  ushort_t* TPP = (ushort_t*)alloc((size_t)NPATH*512*2);
  ushort_t* VAC = (ushort_t*)alloc((size_t)NNODE*336*2);   // [emb|pad|Ua|pad|Uc|pad]
  ushort_t* VP  = (ushort_t*)alloc((size_t)NPATH*224*2);   // [emb|pad|Up|pad]
  ushort_t* RB  = (ushort_t*)alloc((size_t)NBT*512*2);
  ushort_t* RWB = (ushort_t*)alloc((size_t)NBT*112*2);
  ushort_t* WAB = (ushort_t*)alloc(512*2);
  float* cwT  = (float*)alloc((size_t)NBT*100*4);
  float* awT  = (float*)alloc((size_t)NBT*100*4);
  float* rnn  = (float*)alloc((size_t)NBT*950*4);
  ushort_t* preb = (ushort_t*)alloc((size_t)NBT*512*2);
  float* lstm = (float*)alloc((size_t)NBT*128*4);
  float* wbuf = (float*)alloc((size_t)NBT*4);
  float* WfcT = (float*)alloc((size_t)378*100*4);

  auto gg = [](int M, int Npad){ return dim3((unsigned)((M+127)/128), (unsigned)((Npad+63)/64)); };

  // pack embeddings + Wattn
  pack_emb<<<(NNODE*112+255)/256, 256, 0, stream>>>(node_emb, VAC, NNODE, 336);
  pack_emb<<<(NPATH*112+255)/256, 256, 0, stream>>>(path_emb, VP, NPATH, 224);
  pack_wattn<<<2, 256, 0, stream>>>(Wattn, WAB);

  // table GEMMs (Wna/Wia pushed through gathers), bf16 outputs
  gemm_mfma<true><<<gg(NNODE,512),256,0,stream>>>(node_emb,100, Wna,    500, T0A,     512, NNODE,500,512,100, nullptr,nullptr);
  gemm_mfma<true><<<gg(NNODE,512),256,0,stream>>>(node_emb,100, Wna+100,500, T0C,     512, NNODE,500,512,100, nullptr,nullptr);
  gemm_mfma<true><<<gg(NPATH,512),256,0,stream>>>(path_emb,100, Wna+200,500, TPP,     512, NPATH,500,512,100, nullptr,nullptr);
  gemm_mfma<true><<<gg(NNODE,112),256,0,stream>>>(node_emb,100, Wia,    500, VAC+112, 336, NNODE,100,112,100, nullptr,nullptr);
  gemm_mfma<true><<<gg(NNODE,112),256,0,stream>>>(node_emb,100, Wia+100,500, VAC+224, 336, NNODE,100,112,100, nullptr,nullptr);
  gemm_mfma<true><<<gg(NPATH,112),256,0,stream>>>(path_emb,100, Wia+200,500, VP+112,  224, NPATH,100,112,100, nullptr,nullptr);
  // per-(b,t) contributions (biases folded)
  gemm_mfma<true><<<gg(NBT,512),256,0,stream>>>(x,1330, Wna+300,500, RB,  512, NBT,500,512,200, bna,nullptr);
  gemm_mfma<true><<<gg(NBT,112),256,0,stream>>>(x,1330, Wia+300,500, RWB, 112, NBT,100,112,200, bia,nullptr);
  // bert_vec directly into rnn[850:950] (fp32)
  gemm_mfma<false><<<gg(NBT,100),256,0,stream>>>(x+500,1330, Wb,768, rnn+850, 950, NBT,100,100,768, bb,nullptr);

  cw2_kernel<<<NBT,256,0,stream>>>(x, T0A, T0C, TPP, RB, WAB, battn, cwT);
  aw_kernel<<<CB*CMCL,64,0,stream>>>(cwT, awT);
  fuse2_kernel<<<NBT,256,0,stream>>>(x, VAC, VP, RWB, awT, kc_emb, rnn);

  // LSTM pre-activations (bf16 out) + MFMA recurrence
  gemm_mfma<true><<<gg(NBT,512),256,0,stream>>>(rnn,950, Wih,950, preb, 512, NBT,512,512,950, bih,bhh);
  lstm_mfma_kernel<<<2,512,0,stream>>>(preb, Whh, lstm);

  w_kernel<<<NBT,64,0,stream>>>(rnn, Wt, bt0, wbuf);
  transpose_wfc<<<(100*378+255)/256,256,0,stream>>>(Wfc, WfcT);
  final_kernel<<<NBT,256,0,stream>>>(x, wbuf, lstm, WfcT, bfc, out);
}

// Round 5
// 788.171 us; speedup vs baseline: 1.5220x; 1.5220x over previous
//
#include <hip/hip_runtime.h>
#include <math.h>

typedef unsigned short ushort_t;
typedef __attribute__((ext_vector_type(8))) short bf16x8;
typedef __attribute__((ext_vector_type(4))) float f32x4;

// Problem constants
constexpr int CB = 16, CT = 100, CMCL = 100, CDIN = 200;
constexpr int CKC = 50, CHID = 128;
constexpr int XCH = 1330;
constexpr int NBT = CB * CT;       // 1600
constexpr int NNODE = 10002, NPATH = 20002;
constexpr int TRS = 114;           // tr_s ushort stride: 57 dwords, odd -> conflict-free
constexpr int HSTR = 136;          // lstm H row stride (ushorts): 272B, b128-aligned

__device__ __forceinline__ float frcp(float v){ return __builtin_amdgcn_rcpf(v); }
__device__ __forceinline__ float fsigmoid(float v){ return frcp(1.f + __expf(-v)); }
__device__ __forceinline__ float ftanh_(float v){
  float e = __expf(-2.f*fabsf(v));
  return copysignf((1.f - e) * frcp(1.f + e), v);
}
__device__ __forceinline__ float wredsum(float v){
  #pragma unroll
  for (int off = 32; off; off >>= 1) v += __shfl_xor(v, off);
  return v;
}
__device__ __forceinline__ float wredmax(float v){
  #pragma unroll
  for (int off = 32; off; off >>= 1) v = fmaxf(v, __shfl_xor(v, off));
  return v;
}
__device__ __forceinline__ ushort_t f2b(float f){
  union { float f; unsigned u; } c{f};
  return (ushort_t)((c.u + 0x7FFFu + ((c.u >> 16) & 1u)) >> 16);
}
__device__ __forceinline__ float b2f(unsigned hbits){
  union { unsigned u; float f; } c{hbits << 16};
  return c.f;
}
__device__ __forceinline__ void b8f(const ushort_t* p, float* o){
  uint4 v = *reinterpret_cast<const uint4*>(p);
  o[0]=b2f(v.x & 0xFFFFu); o[1]=b2f(v.x >> 16);
  o[2]=b2f(v.y & 0xFFFFu); o[3]=b2f(v.y >> 16);
  o[4]=b2f(v.z & 0xFFFFu); o[5]=b2f(v.z >> 16);
  o[6]=b2f(v.w & 0xFFFFu); o[7]=b2f(v.w >> 16);
}

// ---------------- MFMA bf16 GEMM: C = A(MxK,f32) * B(NxK,f32)^T (+bias) ----------------
// OMODE: 0 = f32 out, 1 = bf16 out, 2 = bf16 out in LSTM P2 fragment layout
template<int OMODE>
__global__ __launch_bounds__(256) void gemm_mfma(
    const float* __restrict__ A, int lda,
    const float* __restrict__ B, int ldb,
    void* __restrict__ Cv, int ldc,
    int M, int N, int Npad, int K,
    const float* __restrict__ bias1, const float* __restrict__ bias2)
{
  __shared__ ushort_t As[128][40];
  __shared__ ushort_t Bs[64][40];
  const int tid = threadIdx.x;
  const int lane = tid & 63, wid = tid >> 6;
  const int wm = wid & 1, wn = wid >> 1;
  const int bm = blockIdx.x * 128, bn = blockIdx.y * 64;
  const int lr = lane & 15, lk = (lane >> 4) * 8;

  f32x4 acc[4][2];
  #pragma unroll
  for (int i = 0; i < 4; ++i)
    #pragma unroll
    for (int j = 0; j < 2; ++j) acc[i][j] = f32x4{0.f,0.f,0.f,0.f};

  const int arow = tid >> 1, akh = (tid & 1) * 16;
  const int brow = tid >> 2, bkh = (tid & 3) * 8;
  const int nk = (K + 31) / 32;
  for (int ks = 0; ks < nk; ++ks) {
    const int k0 = ks * 32;
    {
      int gm = bm + arow;
      const float* ap = A + (long)gm * lda + k0 + akh;
      #pragma unroll
      for (int j = 0; j < 8; ++j) {
        int kk = k0 + akh + 2*j;
        float2 v = make_float2(0.f, 0.f);
        if (gm < M && kk + 2 <= K) v = *reinterpret_cast<const float2*>(ap + 2*j);
        As[arow][akh + 2*j]     = f2b(v.x);
        As[arow][akh + 2*j + 1] = f2b(v.y);
      }
    }
    {
      int gn = bn + brow;
      const float* bp = B + (long)gn * ldb + k0 + bkh;
      #pragma unroll
      for (int j = 0; j < 4; ++j) {
        int kk = k0 + bkh + 2*j;
        float2 v = make_float2(0.f, 0.f);
        if (gn < N && kk + 2 <= K) v = *reinterpret_cast<const float2*>(bp + 2*j);
        Bs[brow][bkh + 2*j]     = f2b(v.x);
        Bs[brow][bkh + 2*j + 1] = f2b(v.y);
      }
    }
    __syncthreads();
    bf16x8 af[4], bf[2];
    #pragma unroll
    for (int i = 0; i < 4; ++i)
      af[i] = *reinterpret_cast<const bf16x8*>(&As[wm*64 + i*16 + lr][lk]);
    #pragma unroll
    for (int j = 0; j < 2; ++j)
      bf[j] = *reinterpret_cast<const bf16x8*>(&Bs[wn*32 + j*16 + lr][lk]);
    #pragma unroll
    for (int i = 0; i < 4; ++i)
      #pragma unroll
      for (int j = 0; j < 2; ++j)
        acc[i][j] = __builtin_amdgcn_mfma_f32_16x16x32_bf16(af[i], bf[j], acc[i][j], 0, 0, 0);
    __syncthreads();
  }
  #pragma unroll
  for (int i = 0; i < 4; ++i) {
    #pragma unroll
    for (int j = 0; j < 2; ++j) {
      #pragma unroll
      for (int r = 0; r < 4; ++r) {
        int gr = bm + wm*64 + i*16 + (lane >> 4)*4 + r;
        int gc = bn + wn*32 + j*16 + lr;
        if (gr < M && gc < Npad) {
          float v = acc[i][j][r];
          if (gc < N) {
            if (bias1) v += bias1[gc];
            if (bias2) v += bias2[gc];
          } else v = 0.f;
          if (OMODE == 2) {
            // P2 layout: ((((t*4+q)*8+w)*4+lkq)*64 + lr2*4 + rr), batch = lkq*4+rr
            int bq = gr / CT, tt = gr % CT;
            int q = gc >> 7, rem = gc & 127, ww = rem >> 4, lr2 = rem & 15;
            int lk2 = bq >> 2, rr = bq & 3;
            ((ushort_t*)Cv)[((((long)tt*4 + q)*8 + ww)*4 + lk2)*64 + lr2*4 + rr] = f2b(v);
          }
          else if (OMODE == 1) ((ushort_t*)Cv)[(long)gr * ldc + gc] = f2b(v);
          else                 ((float*)Cv)[(long)gr * ldc + gc]  = v;
        }
      }
    }
  }
}

// ---------------- pack embeddings: cols 0..111 of a `stride`-wide bf16 row ----------------
__global__ void pack_emb(const float* __restrict__ emb, ushort_t* __restrict__ V, int rows, int stride)
{
  int i = blockIdx.x * 256 + threadIdx.x;
  int r = i / 112, c = i % 112;
  if (r < rows) V[(long)r*stride + c] = (c < 100) ? f2b(emb[(long)r*100 + c]) : (ushort_t)0;
}
__global__ void pack_wattn(const float* __restrict__ Wattn, ushort_t* __restrict__ wab)
{
  int i = blockIdx.x * 256 + threadIdx.x;
  if (i < 512) wab[i] = (i < 500) ? f2b(Wattn[i]) : (ushort_t)0;
}

// ---------------- cw: per (b,t), all m: Wattn . tanh(T0A[a]+T0C[c]+TPP[p]+R) ----------------
__global__ __launch_bounds__(256) void cw2_kernel(
    const float* __restrict__ x, const ushort_t* __restrict__ T0A,
    const ushort_t* __restrict__ T0C, const ushort_t* __restrict__ TPP,
    const ushort_t* __restrict__ RB, const ushort_t* __restrict__ WAB,
    const float* __restrict__ battn, float* __restrict__ cwT)
{
  int bt = blockIdx.x, b = bt / CT, t = bt % CT;
  int tid = threadIdx.x, w = tid >> 6, lane = tid & 63;
  __shared__ int idx_s[300];
  for (int i = tid; i < 300; i += 256) idx_s[i] = (int)x[(long)bt*XCH + 200 + i];
  float rseg[8], wseg[8];
  b8f(RB + (long)bt*512 + lane*8, rseg);
  b8f(WAB + lane*8, wseg);
  __syncthreads();
  float bat = battn[0];

  uint4 A0, C0, P0, A1, C1, P1;
  auto issue = [&](int m, uint4& A, uint4& C, uint4& P){
    if (m < CMCL) {
      int ai = idx_s[3*m], pi = idx_s[3*m+1], ci = idx_s[3*m+2];
      A = *reinterpret_cast<const uint4*>(T0A + (long)ai*512 + lane*8);
      C = *reinterpret_cast<const uint4*>(T0C + (long)ci*512 + lane*8);
      P = *reinterpret_cast<const uint4*>(TPP + (long)pi*512 + lane*8);
    }
  };
  auto proc = [&](int m, const uint4& A, const uint4& C, const uint4& P){
    if (m >= CMCL) return;
    const unsigned ua[4] = {A.x, A.y, A.z, A.w};
    const unsigned uc[4] = {C.x, C.y, C.z, C.w};
    const unsigned up[4] = {P.x, P.y, P.z, P.w};
    float acc = 0.f;
    #pragma unroll
    for (int jj = 0; jj < 4; ++jj) {
      float lo = b2f(ua[jj] & 0xffffu) + b2f(uc[jj] & 0xffffu) + b2f(up[jj] & 0xffffu) + rseg[2*jj];
      float hi = b2f(ua[jj] >> 16)     + b2f(uc[jj] >> 16)     + b2f(up[jj] >> 16)     + rseg[2*jj+1];
      acc = fmaf(ftanh_(lo), wseg[2*jj], acc);
      acc = fmaf(ftanh_(hi), wseg[2*jj+1], acc);
    }
    acc = wredsum(acc);
    if (lane == 0) cwT[((long)b*CMCL + m)*CT + t] = acc + bat;
  };

  issue(w, A0, C0, P0);
  for (int it = 0; it < 25; it += 2) {
    int m0 = w + it*4;
    issue(m0 + 4, A1, C1, P1);
    proc(m0, A0, C0, P0);
    issue(m0 + 8, A0, C0, P0);
    proc(m0 + 4, A1, C1, P1);
  }
}

// ---------------- aw: softmax over t for each (b,m) ----------------
__global__ void aw_kernel(const float* __restrict__ cwT, float* __restrict__ awT)
{
  int bm = blockIdx.x; int lane = threadIdx.x;   // 64 threads
  const float* row = cwT + (long)bm * CT;
  bool h1 = lane < (CT - 64);
  float v0 = row[lane];
  float v1 = h1 ? row[64 + lane] : -3.0e38f;
  float mx = wredmax(fmaxf(v0, v1));
  float e0 = __expf(v0 - mx);
  float e1 = h1 ? __expf(v1 - mx) : 0.f;
  float s = wredsum(e0 + e1);
  float inv = frcp(s);
  awT[(long)bm*CT + lane] = e0 * inv;
  if (h1) awT[(long)bm*CT + 64 + lane] = e1 * inv;
}

// ---------------- fused: na + trans(LDS bf16) + kc-attention -> rnn[0:850] ----------------
__global__ __launch_bounds__(256) void fuse2_kernel(
    const float* __restrict__ x,
    const ushort_t* __restrict__ VAC, const ushort_t* __restrict__ VP,
    const ushort_t* __restrict__ RWB, const float* __restrict__ awT,
    const float* __restrict__ kc_emb, float* __restrict__ rnn)
{
  int bt = blockIdx.x, b = bt / CT, t = bt % CT;
  int tid = threadIdx.x, w = tid >> 6, lane = tid & 63;
  int sub = lane >> 5, li = lane & 31;

  __shared__ ushort_t tr_s[100*TRS];   // 22800 B
  __shared__ float nacc[4][344];
  __shared__ float ia_red[4][104];
  __shared__ float aw_s[100];
  __shared__ int   idx_s[300];
  __shared__ float kcl[CKC];
  __shared__ int   act_k[CKC];
  __shared__ int   nact_s;
  __shared__ float kcn_s, awsum_s;

  for (int i = tid; i < 300; i += 256) idx_s[i] = (int)x[(long)bt*XCH + 200 + i];
  if (tid < 100) aw_s[tid] = awT[((long)b*CMCL + tid)*CT + t];
  if (tid < CKC) kcl[tid] = x[(long)bt*XCH + 1280 + tid];
  __syncthreads();
  if (tid == 0) {
    float kcn = 0.f; int na = 0;
    for (int k = 0; k < CKC; ++k) { float v = kcl[k]; kcn += v; if (v != 0.f) act_k[na++] = k; }
    nact_s = na; kcn_s = (kcn == 0.f) ? 1.f : kcn;
    float s = 0.f;
    for (int m = 0; m < CMCL; ++m) s += aw_s[m];
    awsum_s = s;
  }
  float rwseg[8];
  if (li >= 14 && li < 28) b8f(RWB + (long)bt*112 + (li-14)*8, rwseg);
  __syncthreads();

  // ---- gather phase: 8 m per iteration (4 waves x 2 sub-halves), 2-stage pipeline ----
  float na_a[8] = {}, na_c[8] = {}, na_p[8] = {};
  const bool gv = (li < 28);
  uint4 A0, C0, P0, A1, C1, P1;
  auto g_issue = [&](int m, uint4& A, uint4& C, uint4& P){
    if (m < CMCL && gv) {
      int ai = idx_s[3*m], pi = idx_s[3*m+1], ci = idx_s[3*m+2];
      int eo = li*8, uo = (li-14)*8;
      A = *reinterpret_cast<const uint4*>(VAC + (long)ai*336 + ((li<14) ? eo : 112 + uo));
      C = *reinterpret_cast<const uint4*>(VAC + (long)ci*336 + ((li<14) ? eo : 224 + uo));
      P = *reinterpret_cast<const uint4*>(VP  + (long)pi*224 + eo);
    }
  };
  auto g_proc = [&](int m, const uint4& A, const uint4& C, const uint4& P){
    if (m >= CMCL || !gv) return;
    const unsigned ua[4] = {A.x, A.y, A.z, A.w};
    const unsigned uc[4] = {C.x, C.y, C.z, C.w};
    const unsigned up[4] = {P.x, P.y, P.z, P.w};
    if (li < 14) {
      float awm = aw_s[m];
      #pragma unroll
      for (int jj = 0; jj < 4; ++jj) {
        na_a[2*jj]   = fmaf(awm, b2f(ua[jj] & 0xffffu), na_a[2*jj]);
        na_a[2*jj+1] = fmaf(awm, b2f(ua[jj] >> 16),     na_a[2*jj+1]);
        na_c[2*jj]   = fmaf(awm, b2f(uc[jj] & 0xffffu), na_c[2*jj]);
        na_c[2*jj+1] = fmaf(awm, b2f(uc[jj] >> 16),     na_c[2*jj+1]);
        na_p[2*jj]   = fmaf(awm, b2f(up[jj] & 0xffffu), na_p[2*jj]);
        na_p[2*jj+1] = fmaf(awm, b2f(up[jj] >> 16),     na_p[2*jj+1]);
      }
    } else {
      unsigned* d32 = reinterpret_cast<unsigned*>(&tr_s[m*TRS + (li-14)*8]);
      #pragma unroll
      for (int jj = 0; jj < 4; ++jj) {
        float lo = b2f(ua[jj] & 0xffffu) + b2f(uc[jj] & 0xffffu) + b2f(up[jj] & 0xffffu) + rwseg[2*jj];
        float hi = b2f(ua[jj] >> 16)     + b2f(uc[jj] >> 16)     + b2f(up[jj] >> 16)     + rwseg[2*jj+1];
        d32[jj] = (unsigned)f2b(lo) | ((unsigned)f2b(hi) << 16);
      }
    }
  };
  const int mb = w*2 + sub;
  g_issue(mb, A0, C0, P0);
  for (int it = 0; it < 13; it += 2) {
    g_issue((it+1)*8 + mb, A1, C1, P1);
    g_proc(it*8 + mb, A0, C0, P0);
    g_issue((it+2)*8 + mb, A0, C0, P0);
    g_proc((it+1)*8 + mb, A1, C1, P1);
  }
  // combine sub-halves of na
  #pragma unroll
  for (int j = 0; j < 8; ++j) {
    na_a[j] += __shfl_xor(na_a[j], 32);
    na_c[j] += __shfl_xor(na_c[j], 32);
    na_p[j] += __shfl_xor(na_p[j], 32);
  }
  if (lane < 14) {
    #pragma unroll
    for (int j = 0; j < 8; ++j) {
      nacc[w][      lane*8 + j] = na_a[j];
      nacc[w][112 + lane*8 + j] = na_c[j];
      nacc[w][224 + lane*8 + j] = na_p[j];
    }
  }
  __syncthreads();

  // ---- na epilogue + passthroughs ----
  for (int q = tid; q < 336; q += 256) {
    float v = nacc[0][q] + nacc[1][q] + nacc[2][q] + nacc[3][q];
    int seg = q / 112, col = q % 112;
    if (col < 100) rnn[(long)bt*950 + 350 + seg*100 + col] = v;
  }
  for (int q = tid; q < CDIN; q += 256) {
    float xv = x[(long)bt*XCH + q];
    rnn[(long)bt*950 + 50 + q] = xv;
    rnn[(long)bt*950 + 650 + q] = awsum_s * xv;
  }
  if (tid < CKC) rnn[(long)bt*950 + tid] = kcl[tid];

  // ---- kc attention (dword-pair LDS reads, conflict-free stride) ----
  float ia0 = 0.f, ia1 = 0.f;
  const bool vrow1 = lane < 36;   // owns row 64+lane
  const bool vpv   = lane < 50;   // owns dims 2*lane, 2*lane+1
  const int nact = nact_s;
  const unsigned* tr32_0 = reinterpret_cast<const unsigned*>(&tr_s[lane*TRS]);
  const unsigned* tr32_1 = reinterpret_cast<const unsigned*>(&tr_s[(64+lane)*TRS]);
  const unsigned* tr32   = reinterpret_cast<const unsigned*>(tr_s);
  for (int ki = w; ki < nact; ki += 4) {
    int k = act_k[ki];
    float kck = kcl[k];
    const float* ke = kc_emb + (long)k*100;
    float s0 = 0.f, s1 = 0.f;
    #pragma unroll 5
    for (int dh = 0; dh < 50; ++dh) {
      float k0 = ke[2*dh], k1 = ke[2*dh+1];
      unsigned u0 = tr32_0[dh];
      s0 = fmaf(k0, b2f(u0 & 0xffffu), s0);
      s0 = fmaf(k1, b2f(u0 >> 16), s0);
      if (vrow1) {
        unsigned u1 = tr32_1[dh];
        s1 = fmaf(k0, b2f(u1 & 0xffffu), s1);
        s1 = fmaf(k1, b2f(u1 >> 16), s1);
      }
    }
    s0 *= kck; s1 *= kck;
    float mx = wredmax(fmaxf(s0, vrow1 ? s1 : -3.0e38f));
    float p0e = __expf(s0 - mx);
    float p1e = vrow1 ? __expf(s1 - mx) : 0.f;
    float sm = wredsum(p0e + p1e);
    float inv = kck * frcp(sm);
    p0e *= inv; p1e *= inv;
    #pragma unroll 4
    for (int m = 0; m < CMCL; ++m) {
      float pm = (m < 64) ? __shfl(p0e, m) : __shfl(p1e, m - 64);
      if (vpv) {
        unsigned u = tr32[m*57 + lane];
        ia0 = fmaf(pm, b2f(u & 0xffffu), ia0);
        ia1 = fmaf(pm, b2f(u >> 16), ia1);
      }
    }
  }
  if (vpv) { ia_red[w][2*lane] = ia0; ia_red[w][2*lane+1] = ia1; }
  __syncthreads();
  if (tid < 100) {
    float v = (ia_red[0][tid] + ia_red[1][tid] + ia_red[2][tid] + ia_red[3][tid]) * frcp(kcn_s);
    rnn[(long)bt*950 + 250 + tid] = v;
  }
}

// ---------------- LSTM via MFMA: 1 block, 16 batches, Whh frags in VGPRs, P2-layout pre ----------------
// Wave w owns h indices [16w,16w+16) for all 4 gate classes. Lane (lkq,lr): rows lkq*4+r = batches.
__global__ __launch_bounds__(512) void lstm_mfma2(
    const ushort_t* __restrict__ P2,     // pre-activations in fragment layout
    const float* __restrict__ Whh,       // (512,128) f32
    float* __restrict__ lstm_out)        // (B,T,128) f32
{
  const int tid = threadIdx.x, lane = tid & 63, w = tid >> 6;
  const int lr = lane & 15, lkq = lane >> 4;
  __shared__ ushort_t H[2][16 * HSTR];
  {
    ushort_t* hp = &H[0][0];
    for (int i = tid; i < 2*16*HSTR; i += 512) hp[i] = 0;
  }

  // Whh B-frags in registers: class q covers gates n0 = q*128 + w*16 + lr
  bf16x8 bw0[4], bw1[4], bw2[4], bw3[4];
  #pragma unroll
  for (int kk = 0; kk < 4; ++kk) {
    short s[8];
    const float* wp0 = Whh + (long)(0*128 + w*16 + lr) * 128 + kk*32 + lkq*8;
    const float* wp1 = Whh + (long)(1*128 + w*16 + lr) * 128 + kk*32 + lkq*8;
    const float* wp2 = Whh + (long)(2*128 + w*16 + lr) * 128 + kk*32 + lkq*8;
    const float* wp3 = Whh + (long)(3*128 + w*16 + lr) * 128 + kk*32 + lkq*8;
    #pragma unroll
    for (int j = 0; j < 8; ++j) s[j] = (short)f2b(wp0[j]);
    bw0[kk] = bf16x8{s[0],s[1],s[2],s[3],s[4],s[5],s[6],s[7]};
    #pragma unroll
    for (int j = 0; j < 8; ++j) s[j] = (short)f2b(wp1[j]);
    bw1[kk] = bf16x8{s[0],s[1],s[2],s[3],s[4],s[5],s[6],s[7]};
    #pragma unroll
    for (int j = 0; j < 8; ++j) s[j] = (short)f2b(wp2[j]);
    bw2[kk] = bf16x8{s[0],s[1],s[2],s[3],s[4],s[5],s[6],s[7]};
    #pragma unroll
    for (int j = 0; j < 8; ++j) s[j] = (short)f2b(wp3[j]);
    bw3[kk] = bf16x8{s[0],s[1],s[2],s[3],s[4],s[5],s[6],s[7]};
  }

  // per-step pre loads: 4 coalesced uint2 (8B) per thread
  auto pptr = [&](int t, int q){
    return reinterpret_cast<const uint2*>(P2 + (((((long)t*4 + q)*8 + w)*4 + lkq)*64 + lr*4));
  };
  uint2 pc0 = *pptr(0,0), pc1 = *pptr(0,1), pc2 = *pptr(0,2), pc3 = *pptr(0,3);
  uint2 pn0, pn1, pn2, pn3;
  f32x4 c = {0.f,0.f,0.f,0.f};
  __syncthreads();

  int pb = 0;
  for (int t = 0; t < CT; ++t) {
    if (t + 1 < CT) { pn0 = *pptr(t+1,0); pn1 = *pptr(t+1,1); pn2 = *pptr(t+1,2); pn3 = *pptr(t+1,3); }
    bf16x8 a[4];
    #pragma unroll
    for (int kk = 0; kk < 4; ++kk)
      a[kk] = *reinterpret_cast<const bf16x8*>(&H[pb][lr*HSTR + kk*32 + lkq*8]);
    f32x4 acc0 = f32x4{ b2f(pc0.x & 0xffffu), b2f(pc0.x >> 16), b2f(pc0.y & 0xffffu), b2f(pc0.y >> 16) };
    f32x4 acc1 = f32x4{ b2f(pc1.x & 0xffffu), b2f(pc1.x >> 16), b2f(pc1.y & 0xffffu), b2f(pc1.y >> 16) };
    f32x4 acc2 = f32x4{ b2f(pc2.x & 0xffffu), b2f(pc2.x >> 16), b2f(pc2.y & 0xffffu), b2f(pc2.y >> 16) };
    f32x4 acc3 = f32x4{ b2f(pc3.x & 0xffffu), b2f(pc3.x >> 16), b2f(pc3.y & 0xffffu), b2f(pc3.y >> 16) };
    #pragma unroll
    for (int kk = 0; kk < 4; ++kk) {
      acc0 = __builtin_amdgcn_mfma_f32_16x16x32_bf16(a[kk], bw0[kk], acc0, 0,0,0);
      acc1 = __builtin_amdgcn_mfma_f32_16x16x32_bf16(a[kk], bw1[kk], acc1, 0,0,0);
      acc2 = __builtin_amdgcn_mfma_f32_16x16x32_bf16(a[kk], bw2[kk], acc2, 0,0,0);
      acc3 = __builtin_amdgcn_mfma_f32_16x16x32_bf16(a[kk], bw3[kk], acc3, 0,0,0);
    }
    #pragma unroll
    for (int r = 0; r < 4; ++r) {
      float ig = fsigmoid(acc0[r]);
      float fg = fsigmoid(acc1[r]);
      float gg = ftanh_(acc2[r]);
      float og = fsigmoid(acc3[r]);
      c[r] = fg*c[r] + ig*gg;
      float h = og * ftanh_(c[r]);
      int row = lkq*4 + r;            // batch
      H[pb^1][row*HSTR + w*16 + lr] = f2b(h);
      lstm_out[((long)row*CT + t)*128 + w*16 + lr] = h;
    }
    __syncthreads();
    pb ^= 1;
    pc0 = pn0; pc1 = pn1; pc2 = pn2; pc3 = pn3;
  }
}

// ---------------- w: dot over [bert_vec, kc, ia] segments of rnn ----------------
__global__ void w_kernel(const float* __restrict__ rnn, const float* __restrict__ Wt,
                         const float* __restrict__ bt0, float* __restrict__ wbuf)
{
  int bt = blockIdx.x; int lane = threadIdx.x; // 64 threads
  float acc = 0.f;
  for (int i = lane; i < 250; i += 64) {
    float f;
    if (i < 100)      f = rnn[(long)bt*950 + 850 + i];
    else if (i < 150) f = rnn[(long)bt*950 + (i - 100)];
    else              f = rnn[(long)bt*950 + 250 + (i - 150)];
    acc = fmaf(Wt[i], f, acc);
  }
  acc = wredsum(acc);
  if (lane == 0) wbuf[bt] = acc + bt0[0];
}

__global__ void transpose_wfc(const float* __restrict__ Wfc, float* __restrict__ WfcT)
{
  int i = blockIdx.x*256 + threadIdx.x;
  if (i < 100*378) { int o = i / 378, q = i % 378; WfcT[q*100 + o] = Wfc[i]; }
}

// ---------------- final: causal attention + attended + FC + sigmoid ----------------
__global__ __launch_bounds__(256) void final_kernel(
    const float* __restrict__ x, const float* __restrict__ wbuf,
    const float* __restrict__ lstm_out, const float* __restrict__ WfcT,
    const float* __restrict__ bfc, float* __restrict__ out)
{
  int bt = blockIdx.x; int b = bt / CT, i = bt % CT;
  int tid = threadIdx.x;
  __shared__ float p_s[CT];
  __shared__ float feat_s[384];
  if (tid < 64) {
    bool h1 = (64 + tid) < CT;
    float v0 = (tid <= i) ? wbuf[(long)b*CT + tid] : -3.0e38f;
    float v1 = (h1 && (64 + tid) <= i) ? wbuf[(long)b*CT + 64 + tid] : -3.0e38f;
    float mx = wredmax(fmaxf(v0, v1));
    float e0 = (tid <= i) ? __expf(v0 - mx) : 0.f;
    float e1 = (h1 && (64 + tid) <= i) ? __expf(v1 - mx) : 0.f;
    float s = wredsum(e0 + e1);
    float inv = frcp(s);
    p_s[tid] = e0 * inv;
    if (h1) p_s[64 + tid] = e1 * inv;
  }
  __syncthreads();
  if (tid < CHID) {
    float cur = 0.f;
    #pragma unroll 4
    for (int j = 0; j <= i; ++j) cur = fmaf(p_s[j], lstm_out[((long)b*CT + j)*CHID + tid], cur);
    float l = lstm_out[((long)b*CT + i)*CHID + tid];
    float att;
    if (i == 0) att = l;
    else { att = 0.5f * l; if (i <= CT - 2) att = fmaf(0.5f, cur, att); }
    feat_s[250 + tid] = att;
  }
  for (int q = tid; q < 250; q += 256)
    feat_s[q] = (q < 200) ? x[(long)bt*XCH + q] : x[(long)bt*XCH + 1280 + (q - 200)];
  __syncthreads();
  if (tid < 100) {
    float acc = bfc[tid];
    #pragma unroll 4
    for (int q = 0; q < 378; ++q) acc = fmaf(WfcT[q*100 + tid], feat_s[q], acc);
    out[(long)bt*100 + tid] = fsigmoid(acc);
  }
}

extern "C" void kernel_launch(void* const* d_in, const int* in_sizes, int n_in,
                              void* d_out, int out_size, void* d_ws, size_t ws_size,
                              hipStream_t stream) {
  (void)in_sizes; (void)n_in; (void)out_size; (void)ws_size;
  const float* x        = (const float*)d_in[0];
  const float* node_emb = (const float*)d_in[1];
  const float* path_emb = (const float*)d_in[2];
  const float* Wb       = (const float*)d_in[3];
  const float* bb       = (const float*)d_in[4];
  const float* Wna      = (const float*)d_in[5];
  const float* bna      = (const float*)d_in[6];
  const float* Wia      = (const float*)d_in[7];
  const float* bia      = (const float*)d_in[8];
  const float* Wattn    = (const float*)d_in[9];
  const float* battn    = (const float*)d_in[10];
  const float* kc_emb   = (const float*)d_in[11];
  const float* Wt       = (const float*)d_in[12];
  const float* bt0      = (const float*)d_in[13];
  const float* Wih      = (const float*)d_in[14];
  const float* Whh      = (const float*)d_in[15];
  const float* bih      = (const float*)d_in[16];
  const float* bhh      = (const float*)d_in[17];
  const float* Wfc      = (const float*)d_in[18];
  const float* bfc      = (const float*)d_in[19];
  float* out = (float*)d_out;

  char* cur = (char*)d_ws;
  auto alloc = [&](size_t bytes)->char* {
    char* p = cur; cur += (bytes + 255) & ~(size_t)255; return p;
  };
  ushort_t* T0A = (ushort_t*)alloc((size_t)NNODE*512*2);
  ushort_t* T0C = (ushort_t*)alloc((size_t)NNODE*512*2);
  ushort_t* TPP = (ushort_t*)alloc((size_t)NPATH*512*2);
  ushort_t* VAC = (ushort_t*)alloc((size_t)NNODE*336*2);   // [emb|pad|Ua|pad|Uc|pad]
  ushort_t* VP  = (ushort_t*)alloc((size_t)NPATH*224*2);   // [emb|pad|Up|pad]
  ushort_t* RB  = (ushort_t*)alloc((size_t)NBT*512*2);
  ushort_t* RWB = (ushort_t*)alloc((size_t)NBT*112*2);
  ushort_t* WAB = (ushort_t*)alloc(512*2);
  float* cwT  = (float*)alloc((size_t)NBT*100*4);
  float* awT  = (float*)alloc((size_t)NBT*100*4);
  float* rnn  = (float*)alloc((size_t)NBT*950*4);
  ushort_t* P2 = (ushort_t*)alloc((size_t)NBT*512*2);      // pre in LSTM fragment layout
  float* lstm = (float*)alloc((size_t)NBT*128*4);
  float* wbuf = (float*)alloc((size_t)NBT*4);
  float* WfcT = (float*)alloc((size_t)378*100*4);

  auto gg = [](int M, int Npad){ return dim3((unsigned)((M+127)/128), (unsigned)((Npad+63)/64)); };

  // pack embeddings + Wattn
  pack_emb<<<(NNODE*112+255)/256, 256, 0, stream>>>(node_emb, VAC, NNODE, 336);
  pack_emb<<<(NPATH*112+255)/256, 256, 0, stream>>>(path_emb, VP, NPATH, 224);
  pack_wattn<<<2, 256, 0, stream>>>(Wattn, WAB);

  // table GEMMs (Wna/Wia pushed through gathers), bf16 outputs
  gemm_mfma<1><<<gg(NNODE,512),256,0,stream>>>(node_emb,100, Wna,    500, T0A,     512, NNODE,500,512,100, nullptr,nullptr);
  gemm_mfma<1><<<gg(NNODE,512),256,0,stream>>>(node_emb,100, Wna+100,500, T0C,     512, NNODE,500,512,100, nullptr,nullptr);
  gemm_mfma<1><<<gg(NPATH,512),256,0,stream>>>(path_emb,100, Wna+200,500, TPP,     512, NPATH,500,512,100, nullptr,nullptr);
  gemm_mfma<1><<<gg(NNODE,112),256,0,stream>>>(node_emb,100, Wia,    500, VAC+112, 336, NNODE,100,112,100, nullptr,nullptr);
  gemm_mfma<1><<<gg(NNODE,112),256,0,stream>>>(node_emb,100, Wia+100,500, VAC+224, 336, NNODE,100,112,100, nullptr,nullptr);
  gemm_mfma<1><<<gg(NPATH,112),256,0,stream>>>(path_emb,100, Wia+200,500, VP+112,  224, NPATH,100,112,100, nullptr,nullptr);
  // per-(b,t) contributions (biases folded)
  gemm_mfma<1><<<gg(NBT,512),256,0,stream>>>(x,1330, Wna+300,500, RB,  512, NBT,500,512,200, bna,nullptr);
  gemm_mfma<1><<<gg(NBT,112),256,0,stream>>>(x,1330, Wia+300,500, RWB, 112, NBT,100,112,200, bia,nullptr);
  // bert_vec directly into rnn[850:950] (fp32)
  gemm_mfma<0><<<gg(NBT,100),256,0,stream>>>(x+500,1330, Wb,768, rnn+850, 950, NBT,100,100,768, bb,nullptr);

  cw2_kernel<<<NBT,256,0,stream>>>(x, T0A, T0C, TPP, RB, WAB, battn, cwT);
  aw_kernel<<<CB*CMCL,64,0,stream>>>(cwT, awT);
  fuse2_kernel<<<NBT,256,0,stream>>>(x, VAC, VP, RWB, awT, kc_emb, rnn);

  // LSTM pre-activations in P2 fragment layout + MFMA recurrence (1 block, 16 batches)
  gemm_mfma<2><<<gg(NBT,512),256,0,stream>>>(rnn,950, Wih,950, P2, 0, NBT,512,512,950, bih,bhh);
  lstm_mfma2<<<1,512,0,stream>>>(P2, Whh, lstm);

  w_kernel<<<NBT,64,0,stream>>>(rnn, Wt, bt0, wbuf);
  transpose_wfc<<<(100*378+255)/256,256,0,stream>>>(Wfc, WfcT);
  final_kernel<<<NBT,256,0,stream>>>(x, wbuf, lstm, WfcT, bfc, out);
}

// Round 6
// 650.719 us; speedup vs baseline: 1.8435x; 1.2112x over previous
//
#include <hip/hip_runtime.h>
#include <math.h>

typedef unsigned short ushort_t;
typedef __attribute__((ext_vector_type(8))) short bf16x8;
typedef __attribute__((ext_vector_type(4))) float f32x4;

// Problem constants
constexpr int CB = 16, CT = 100, CMCL = 100, CDIN = 200;
constexpr int CKC = 50, CHID = 128;
constexpr int XCH = 1330;
constexpr int NBT = CB * CT;       // 1600
constexpr int NNODE = 10002, NPATH = 20002;
constexpr int TRS = 114;           // tr_s ushort stride: 57 dwords, odd -> conflict-free
constexpr int HSTR = 136;          // lstm H row stride (ushorts)
constexpr int NODE_W = 1408;       // node table row width: [T0A 512|T0C 512|emb 112|Ua 112|Uc 112|pad]
constexpr int PATH_W = 768;        // path table row width: [TPP 512|emb 112|Up 112|pad]
constexpr int XR_W   = 640;        // x-derived row: [R 512|RW 112|pad]

__device__ __forceinline__ float frcp(float v){ return __builtin_amdgcn_rcpf(v); }
__device__ __forceinline__ float fsigmoid(float v){ return frcp(1.f + __expf(-v)); }
__device__ __forceinline__ float ftanh_(float v){
  float e = __expf(-2.f*fabsf(v));
  return copysignf((1.f - e) * frcp(1.f + e), v);
}
__device__ __forceinline__ float wredsum(float v){
  #pragma unroll
  for (int off = 32; off; off >>= 1) v += __shfl_xor(v, off);
  return v;
}
__device__ __forceinline__ float wredmax(float v){
  #pragma unroll
  for (int off = 32; off; off >>= 1) v = fmaxf(v, __shfl_xor(v, off));
  return v;
}
__device__ __forceinline__ ushort_t f2b(float f){
  union { float f; unsigned u; } c{f};
  return (ushort_t)((c.u + 0x7FFFu + ((c.u >> 16) & 1u)) >> 16);
}
__device__ __forceinline__ float b2f(unsigned hbits){
  union { unsigned u; float f; } c{hbits << 16};
  return c.f;
}
__device__ __forceinline__ void b8f(const ushort_t* p, float* o){
  uint4 v = *reinterpret_cast<const uint4*>(p);
  o[0]=b2f(v.x & 0xFFFFu); o[1]=b2f(v.x >> 16);
  o[2]=b2f(v.y & 0xFFFFu); o[3]=b2f(v.y >> 16);
  o[4]=b2f(v.z & 0xFFFFu); o[5]=b2f(v.z >> 16);
  o[6]=b2f(v.w & 0xFFFFu); o[7]=b2f(v.w >> 16);
}

// ---------------- table GEMM: C[M][Npad](bf16) = A[M][100](f32) @ Bp[Npad][100](f32)^T ----------------
// Whole-K staging (pad to 128), BM=BN=128, 4 waves (2x2), XCD-aware 1-D grid.
__global__ __launch_bounds__(256) void tblgemm(
    const float* __restrict__ A, int M,
    const float* __restrict__ Bp, int Npad,
    ushort_t* __restrict__ C)
{
  constexpr int KS = 136;                  // ushort stride: 68 dw, row base 16B-aligned
  __shared__ ushort_t As[128*KS];
  __shared__ ushort_t Bs[128*KS];
  const int NCB = Npad >> 7;
  const int d = blockIdx.x, xcd = d & 7, s = d >> 3;
  const int y = xcd + 8 * (s / NCB), cb = s % NCB;
  const int bm = y * 128, bn = cb * 128;
  if (bm >= M) return;
  const int tid = threadIdx.x, lane = tid & 63, w = tid >> 6;
  const int wm = w & 1, wn = w >> 1;
  const int lr = lane & 15, lkq = lane >> 4;

  // stage whole K (100 floats -> bf16), zero-pad k in [100,136)
  for (int f = tid; f < 3200; f += 256) {
    int r = f / 25, j4 = (f % 25) * 4;
    int gm = bm + r;
    float4 va = (gm < M) ? *reinterpret_cast<const float4*>(A + (long)gm*100 + j4)
                         : make_float4(0.f,0.f,0.f,0.f);
    uint2 pa; pa.x = (unsigned)f2b(va.x) | ((unsigned)f2b(va.y) << 16);
    pa.y = (unsigned)f2b(va.z) | ((unsigned)f2b(va.w) << 16);
    *reinterpret_cast<uint2*>(&As[r*KS + j4]) = pa;
    float4 vb = *reinterpret_cast<const float4*>(Bp + (long)(bn + r)*100 + j4);
    uint2 pb; pb.x = (unsigned)f2b(vb.x) | ((unsigned)f2b(vb.y) << 16);
    pb.y = (unsigned)f2b(vb.z) | ((unsigned)f2b(vb.w) << 16);
    *reinterpret_cast<uint2*>(&Bs[r*KS + j4]) = pb;
  }
  for (int f = tid; f < 128*18; f += 256) {
    int r = f / 18, jd = f % 18;
    reinterpret_cast<unsigned*>(&As[r*KS + 100])[jd] = 0u;
    reinterpret_cast<unsigned*>(&Bs[r*KS + 100])[jd] = 0u;
  }
  __syncthreads();

  f32x4 acc[4][4];
  #pragma unroll
  for (int i = 0; i < 4; ++i)
    #pragma unroll
    for (int j = 0; j < 4; ++j) acc[i][j] = f32x4{0.f,0.f,0.f,0.f};
  #pragma unroll
  for (int ks = 0; ks < 4; ++ks) {
    const int ko = ks*32 + lkq*8;
    bf16x8 af[4], bf[4];
    #pragma unroll
    for (int i = 0; i < 4; ++i)
      af[i] = *reinterpret_cast<const bf16x8*>(&As[(wm*64 + i*16 + lr)*KS + ko]);
    #pragma unroll
    for (int j = 0; j < 4; ++j)
      bf[j] = *reinterpret_cast<const bf16x8*>(&Bs[(wn*64 + j*16 + lr)*KS + ko]);
    #pragma unroll
    for (int i = 0; i < 4; ++i)
      #pragma unroll
      for (int j = 0; j < 4; ++j)
        acc[i][j] = __builtin_amdgcn_mfma_f32_16x16x32_bf16(af[i], bf[j], acc[i][j], 0, 0, 0);
  }
  #pragma unroll
  for (int i = 0; i < 4; ++i) {
    #pragma unroll
    for (int j = 0; j < 4; ++j) {
      #pragma unroll
      for (int r = 0; r < 4; ++r) {
        int gr = bm + wm*64 + i*16 + lkq*4 + r;
        int gc = bn + wn*64 + j*16 + lr;
        if (gr < M) C[(long)gr * Npad + gc] = f2b(acc[i][j][r]);
      }
    }
  }
}

// ---------------- generic MFMA GEMM (XCD-aware 1-D grid): C = A(MxK,f32) @ B(NxK,f32)^T + bias ----------------
// OMODE: 0 = f32 out, 1 = bf16 out, 2 = bf16 out in LSTM P2 fragment layout
template<int OMODE>
__global__ __launch_bounds__(256) void gemm_mfma(
    const float* __restrict__ A, int lda,
    const float* __restrict__ B, int ldb,
    void* __restrict__ Cv, int ldc,
    int M, int N, int Npad, int K,
    const float* __restrict__ bias1, const float* __restrict__ bias2, int NCB)
{
  __shared__ ushort_t As[128][40];
  __shared__ ushort_t Bs[64][40];
  const int d = blockIdx.x, xcd = d & 7, s = d >> 3;
  const int y = xcd + 8 * (s / NCB), cb = s % NCB;
  const int bm = y * 128, bn = cb * 64;
  if (bm >= M) return;
  const int tid = threadIdx.x;
  const int lane = tid & 63, wid = tid >> 6;
  const int wm = wid & 1, wn = wid >> 1;
  const int lr = lane & 15, lk = (lane >> 4) * 8;

  f32x4 acc[4][2];
  #pragma unroll
  for (int i = 0; i < 4; ++i)
    #pragma unroll
    for (int j = 0; j < 2; ++j) acc[i][j] = f32x4{0.f,0.f,0.f,0.f};

  const int arow = tid >> 1, akh = (tid & 1) * 16;
  const int brow = tid >> 2, bkh = (tid & 3) * 8;
  const int nk = (K + 31) / 32;
  for (int ks = 0; ks < nk; ++ks) {
    const int k0 = ks * 32;
    {
      int gm = bm + arow;
      const float* ap = A + (long)gm * lda + k0 + akh;
      #pragma unroll
      for (int j = 0; j < 8; ++j) {
        int kk = k0 + akh + 2*j;
        float2 v = make_float2(0.f, 0.f);
        if (gm < M && kk + 2 <= K) v = *reinterpret_cast<const float2*>(ap + 2*j);
        As[arow][akh + 2*j]     = f2b(v.x);
        As[arow][akh + 2*j + 1] = f2b(v.y);
      }
    }
    {
      int gn = bn + brow;
      const float* bp = B + (long)gn * ldb + k0 + bkh;
      #pragma unroll
      for (int j = 0; j < 4; ++j) {
        int kk = k0 + bkh + 2*j;
        float2 v = make_float2(0.f, 0.f);
        if (gn < N && kk + 2 <= K) v = *reinterpret_cast<const float2*>(bp + 2*j);
        Bs[brow][bkh + 2*j]     = f2b(v.x);
        Bs[brow][bkh + 2*j + 1] = f2b(v.y);
      }
    }
    __syncthreads();
    bf16x8 af[4], bf[2];
    #pragma unroll
    for (int i = 0; i < 4; ++i)
      af[i] = *reinterpret_cast<const bf16x8*>(&As[wm*64 + i*16 + lr][lk]);
    #pragma unroll
    for (int j = 0; j < 2; ++j)
      bf[j] = *reinterpret_cast<const bf16x8*>(&Bs[wn*32 + j*16 + lr][lk]);
    #pragma unroll
    for (int i = 0; i < 4; ++i)
      #pragma unroll
      for (int j = 0; j < 2; ++j)
        acc[i][j] = __builtin_amdgcn_mfma_f32_16x16x32_bf16(af[i], bf[j], acc[i][j], 0, 0, 0);
    __syncthreads();
  }
  #pragma unroll
  for (int i = 0; i < 4; ++i) {
    #pragma unroll
    for (int j = 0; j < 2; ++j) {
      #pragma unroll
      for (int r = 0; r < 4; ++r) {
        int gr = bm + wm*64 + i*16 + (lane >> 4)*4 + r;
        int gc = bn + wn*32 + j*16 + lr;
        if (gr < M && gc < Npad) {
          float v = acc[i][j][r];
          if (gc < N) {
            if (bias1) v += bias1[gc];
            if (bias2) v += bias2[gc];
          } else v = 0.f;
          if (OMODE == 2) {
            int bq = gr / CT, tt = gr % CT;
            int q = gc >> 7, rem = gc & 127, ww = rem >> 4, lr2 = rem & 15;
            int lk2 = bq >> 2, rr = bq & 3;
            ((ushort_t*)Cv)[((((long)tt*4 + q)*8 + ww)*4 + lk2)*64 + lr2*4 + rr] = f2b(v);
          }
          else if (OMODE == 1) ((ushort_t*)Cv)[(long)gr * ldc + gc] = f2b(v);
          else                 ((float*)Cv)[(long)gr * ldc + gc]  = v;
        }
      }
    }
  }
}

// ---------------- B-pack kernels ----------------
__global__ void pack_Bn(const float* __restrict__ Wna, const float* __restrict__ Wia, float* __restrict__ Bn)
{
  int i = blockIdx.x*256 + threadIdx.x;
  if (i >= NODE_W*100) return;
  int n = i / 100, k = i % 100;
  float v = 0.f;
  if (n < 500)                      v = Wna[(long)n*500 + k];
  else if (n >= 512 && n < 1012)    v = Wna[(long)(n-512)*500 + 100 + k];
  else if (n >= 1024 && n < 1124)   v = (k == n-1024) ? 1.f : 0.f;
  else if (n >= 1136 && n < 1236)   v = Wia[(long)(n-1136)*500 + k];
  else if (n >= 1248 && n < 1348)   v = Wia[(long)(n-1248)*500 + 100 + k];
  Bn[i] = v;
}
__global__ void pack_Bp(const float* __restrict__ Wna, const float* __restrict__ Wia, float* __restrict__ Bp)
{
  int i = blockIdx.x*256 + threadIdx.x;
  if (i >= PATH_W*100) return;
  int n = i / 100, k = i % 100;
  float v = 0.f;
  if (n < 500)                    v = Wna[(long)n*500 + 200 + k];
  else if (n >= 512 && n < 612)   v = (k == n-512) ? 1.f : 0.f;
  else if (n >= 624 && n < 724)   v = Wia[(long)(n-624)*500 + 200 + k];
  Bp[i] = v;
}
__global__ void pack_Bx(const float* __restrict__ Wna, const float* __restrict__ Wia,
                        const float* __restrict__ bna, const float* __restrict__ bia,
                        float* __restrict__ Bx, float* __restrict__ bias_x)
{
  int i = blockIdx.x*256 + threadIdx.x;
  if (i < XR_W) {
    float b = 0.f;
    if (i < 500) b = bna[i];
    else if (i >= 512 && i < 612) b = bia[i-512];
    bias_x[i] = b;
  }
  if (i >= XR_W*200) return;
  int n = i / 200, k = i % 200;
  float v = 0.f;
  if (n < 500)                  v = Wna[(long)n*500 + 300 + k];
  else if (n >= 512 && n < 612) v = Wia[(long)(n-512)*500 + 300 + k];
  Bx[i] = v;
}
__global__ void pack_wattn(const float* __restrict__ Wattn, ushort_t* __restrict__ wab)
{
  int i = blockIdx.x * 256 + threadIdx.x;
  if (i < 512) wab[i] = (i < 500) ? f2b(Wattn[i]) : (ushort_t)0;
}

// ---------------- cw: per (b,t), all m: Wattn . tanh(T0A[a]+T0C[c]+TPP[p]+R) ----------------
__global__ __launch_bounds__(256) void cw2_kernel(
    const float* __restrict__ x, const ushort_t* __restrict__ NODE_ALL,
    const ushort_t* __restrict__ PATH_ALL, const ushort_t* __restrict__ XR,
    const ushort_t* __restrict__ WAB,
    const float* __restrict__ battn, float* __restrict__ cwT)
{
  int bt = blockIdx.x, b = bt / CT, t = bt % CT;
  int tid = threadIdx.x, w = tid >> 6, lane = tid & 63;
  __shared__ int idx_s[300];
  for (int i = tid; i < 300; i += 256) idx_s[i] = (int)x[(long)bt*XCH + 200 + i];
  float rseg[8], wseg[8];
  b8f(XR + (long)bt*XR_W + lane*8, rseg);
  b8f(WAB + lane*8, wseg);
  __syncthreads();
  float bat = battn[0];

  uint4 A0, C0, P0, A1, C1, P1;
  auto issue = [&](int m, uint4& A, uint4& C, uint4& P){
    if (m < CMCL) {
      int ai = idx_s[3*m], pi = idx_s[3*m+1], ci = idx_s[3*m+2];
      A = *reinterpret_cast<const uint4*>(NODE_ALL + (long)ai*NODE_W + lane*8);
      C = *reinterpret_cast<const uint4*>(NODE_ALL + (long)ci*NODE_W + 512 + lane*8);
      P = *reinterpret_cast<const uint4*>(PATH_ALL + (long)pi*PATH_W + lane*8);
    }
  };
  auto proc = [&](int m, const uint4& A, const uint4& C, const uint4& P){
    if (m >= CMCL) return;
    const unsigned ua[4] = {A.x, A.y, A.z, A.w};
    const unsigned uc[4] = {C.x, C.y, C.z, C.w};
    const unsigned up[4] = {P.x, P.y, P.z, P.w};
    float acc = 0.f;
    #pragma unroll
    for (int jj = 0; jj < 4; ++jj) {
      float lo = b2f(ua[jj] & 0xffffu) + b2f(uc[jj] & 0xffffu) + b2f(up[jj] & 0xffffu) + rseg[2*jj];
      float hi = b2f(ua[jj] >> 16)     + b2f(uc[jj] >> 16)     + b2f(up[jj] >> 16)     + rseg[2*jj+1];
      acc = fmaf(ftanh_(lo), wseg[2*jj], acc);
      acc = fmaf(ftanh_(hi), wseg[2*jj+1], acc);
    }
    acc = wredsum(acc);
    if (lane == 0) cwT[((long)b*CMCL + m)*CT + t] = acc + bat;
  };

  issue(w, A0, C0, P0);
  for (int it = 0; it < 25; it += 2) {
    int m0 = w + it*4;
    issue(m0 + 4, A1, C1, P1);
    proc(m0, A0, C0, P0);
    issue(m0 + 8, A0, C0, P0);
    proc(m0 + 4, A1, C1, P1);
  }
}

// ---------------- aw: softmax over t for each (b,m) ----------------
__global__ void aw_kernel(const float* __restrict__ cwT, float* __restrict__ awT)
{
  int bm = blockIdx.x; int lane = threadIdx.x;   // 64 threads
  const float* row = cwT + (long)bm * CT;
  bool h1 = lane < (CT - 64);
  float v0 = row[lane];
  float v1 = h1 ? row[64 + lane] : -3.0e38f;
  float mx = wredmax(fmaxf(v0, v1));
  float e0 = __expf(v0 - mx);
  float e1 = h1 ? __expf(v1 - mx) : 0.f;
  float s = wredsum(e0 + e1);
  float inv = frcp(s);
  awT[(long)bm*CT + lane] = e0 * inv;
  if (h1) awT[(long)bm*CT + 64 + lane] = e1 * inv;
}

// ---------------- fused: na + trans(LDS bf16) + kc-attention -> rnn[0:850] ----------------
__global__ __launch_bounds__(256) void fuse2_kernel(
    const float* __restrict__ x,
    const ushort_t* __restrict__ NODE_ALL, const ushort_t* __restrict__ PATH_ALL,
    const ushort_t* __restrict__ XR, const float* __restrict__ awT,
    const float* __restrict__ kc_emb, float* __restrict__ rnn)
{
  int bt = blockIdx.x, b = bt / CT, t = bt % CT;
  int tid = threadIdx.x, w = tid >> 6, lane = tid & 63;
  int sub = lane >> 5, li = lane & 31;

  __shared__ ushort_t tr_s[100*TRS];
  __shared__ float nacc[4][344];
  __shared__ float ia_red[4][104];
  __shared__ float aw_s[100];
  __shared__ int   idx_s[300];
  __shared__ float kcl[CKC];
  __shared__ int   act_k[CKC];
  __shared__ int   nact_s;
  __shared__ float kcn_s, awsum_s;

  for (int i = tid; i < 300; i += 256) idx_s[i] = (int)x[(long)bt*XCH + 200 + i];
  if (tid < 100) aw_s[tid] = awT[((long)b*CMCL + tid)*CT + t];
  if (tid < CKC) kcl[tid] = x[(long)bt*XCH + 1280 + tid];
  __syncthreads();
  if (tid == 0) {
    float kcn = 0.f; int na = 0;
    for (int k = 0; k < CKC; ++k) { float v = kcl[k]; kcn += v; if (v != 0.f) act_k[na++] = k; }
    nact_s = na; kcn_s = (kcn == 0.f) ? 1.f : kcn;
    float s = 0.f;
    for (int m = 0; m < CMCL; ++m) s += aw_s[m];
    awsum_s = s;
  }
  float rwseg[8];
  if (li >= 14 && li < 28) b8f(XR + (long)bt*XR_W + 512 + (li-14)*8, rwseg);
  __syncthreads();

  // ---- gather phase ----
  float na_a[8] = {}, na_c[8] = {}, na_p[8] = {};
  const bool gv = (li < 28);
  uint4 A0, C0, P0, A1, C1, P1;
  auto g_issue = [&](int m, uint4& A, uint4& C, uint4& P){
    if (m < CMCL && gv) {
      int ai = idx_s[3*m], pi = idx_s[3*m+1], ci = idx_s[3*m+2];
      int eo = li*8, uo = (li-14)*8;
      A = *reinterpret_cast<const uint4*>(NODE_ALL + (long)ai*NODE_W + 1024 + eo);
      C = *reinterpret_cast<const uint4*>(NODE_ALL + (long)ci*NODE_W + ((li<14) ? 1024 + eo : 1248 + uo));
      P = *reinterpret_cast<const uint4*>(PATH_ALL + (long)pi*PATH_W + 512 + eo);
    }
  };
  auto g_proc = [&](int m, const uint4& A, const uint4& C, const uint4& P){
    if (m >= CMCL || !gv) return;
    const unsigned ua[4] = {A.x, A.y, A.z, A.w};
    const unsigned uc[4] = {C.x, C.y, C.z, C.w};
    const unsigned up[4] = {P.x, P.y, P.z, P.w};
    if (li < 14) {
      float awm = aw_s[m];
      #pragma unroll
      for (int jj = 0; jj < 4; ++jj) {
        na_a[2*jj]   = fmaf(awm, b2f(ua[jj] & 0xffffu), na_a[2*jj]);
        na_a[2*jj+1] = fmaf(awm, b2f(ua[jj] >> 16),     na_a[2*jj+1]);
        na_c[2*jj]   = fmaf(awm, b2f(uc[jj] & 0xffffu), na_c[2*jj]);
        na_c[2*jj+1] = fmaf(awm, b2f(uc[jj] >> 16),     na_c[2*jj+1]);
        na_p[2*jj]   = fmaf(awm, b2f(up[jj] & 0xffffu), na_p[2*jj]);
        na_p[2*jj+1] = fmaf(awm, b2f(up[jj] >> 16),     na_p[2*jj+1]);
      }
    } else {
      unsigned* d32 = reinterpret_cast<unsigned*>(&tr_s[m*TRS + (li-14)*8]);
      #pragma unroll
      for (int jj = 0; jj < 4; ++jj) {
        float lo = b2f(ua[jj] & 0xffffu) + b2f(uc[jj] & 0xffffu) + b2f(up[jj] & 0xffffu) + rwseg[2*jj];
        float hi = b2f(ua[jj] >> 16)     + b2f(uc[jj] >> 16)     + b2f(up[jj] >> 16)     + rwseg[2*jj+1];
        d32[jj] = (unsigned)f2b(lo) | ((unsigned)f2b(hi) << 16);
      }
    }
  };
  const int mb = w*2 + sub;
  g_issue(mb, A0, C0, P0);
  for (int it = 0; it < 13; it += 2) {
    g_issue((it+1)*8 + mb, A1, C1, P1);
    g_proc(it*8 + mb, A0, C0, P0);
    g_issue((it+2)*8 + mb, A0, C0, P0);
    g_proc((it+1)*8 + mb, A1, C1, P1);
  }
  #pragma unroll
  for (int j = 0; j < 8; ++j) {
    na_a[j] += __shfl_xor(na_a[j], 32);
    na_c[j] += __shfl_xor(na_c[j], 32);
    na_p[j] += __shfl_xor(na_p[j], 32);
  }
  if (lane < 14) {
    #pragma unroll
    for (int j = 0; j < 8; ++j) {
      nacc[w][      lane*8 + j] = na_a[j];
      nacc[w][112 + lane*8 + j] = na_c[j];
      nacc[w][224 + lane*8 + j] = na_p[j];
    }
  }
  __syncthreads();

  for (int q = tid; q < 336; q += 256) {
    float v = nacc[0][q] + nacc[1][q] + nacc[2][q] + nacc[3][q];
    int seg = q / 112, col = q % 112;
    if (col < 100) rnn[(long)bt*950 + 350 + seg*100 + col] = v;
  }
  for (int q = tid; q < CDIN; q += 256) {
    float xv = x[(long)bt*XCH + q];
    rnn[(long)bt*950 + 50 + q] = xv;
    rnn[(long)bt*950 + 650 + q] = awsum_s * xv;
  }
  if (tid < CKC) rnn[(long)bt*950 + tid] = kcl[tid];

  // ---- kc attention ----
  float ia0 = 0.f, ia1 = 0.f;
  const bool vrow1 = lane < 36;
  const bool vpv   = lane < 50;
  const int nact = nact_s;
  const unsigned* tr32_0 = reinterpret_cast<const unsigned*>(&tr_s[lane*TRS]);
  const unsigned* tr32_1 = reinterpret_cast<const unsigned*>(&tr_s[(64+lane)*TRS]);
  const unsigned* tr32   = reinterpret_cast<const unsigned*>(tr_s);
  for (int ki = w; ki < nact; ki += 4) {
    int k = act_k[ki];
    float kck = kcl[k];
    const float* ke = kc_emb + (long)k*100;
    float s0 = 0.f, s1 = 0.f;
    #pragma unroll 5
    for (int dh = 0; dh < 50; ++dh) {
      float k0 = ke[2*dh], k1 = ke[2*dh+1];
      unsigned u0 = tr32_0[dh];
      s0 = fmaf(k0, b2f(u0 & 0xffffu), s0);
      s0 = fmaf(k1, b2f(u0 >> 16), s0);
      if (vrow1) {
        unsigned u1 = tr32_1[dh];
        s1 = fmaf(k0, b2f(u1 & 0xffffu), s1);
        s1 = fmaf(k1, b2f(u1 >> 16), s1);
      }
    }
    s0 *= kck; s1 *= kck;
    float mx = wredmax(fmaxf(s0, vrow1 ? s1 : -3.0e38f));
    float p0e = __expf(s0 - mx);
    float p1e = vrow1 ? __expf(s1 - mx) : 0.f;
    float sm = wredsum(p0e + p1e);
    float inv = kck * frcp(sm);
    p0e *= inv; p1e *= inv;
    #pragma unroll 4
    for (int m = 0; m < CMCL; ++m) {
      float pm = (m < 64) ? __shfl(p0e, m) : __shfl(p1e, m - 64);
      if (vpv) {
        unsigned u = tr32[m*57 + lane];
        ia0 = fmaf(pm, b2f(u & 0xffffu), ia0);
        ia1 = fmaf(pm, b2f(u >> 16), ia1);
      }
    }
  }
  if (vpv) { ia_red[w][2*lane] = ia0; ia_red[w][2*lane+1] = ia1; }
  __syncthreads();
  if (tid < 100) {
    float v = (ia_red[0][tid] + ia_red[1][tid] + ia_red[2][tid] + ia_red[3][tid]) * frcp(kcn_s);
    rnn[(long)bt*950 + 250 + tid] = v;
  }
}

// ---------------- LSTM via MFMA: 1 block, 16 batches, Whh frags in VGPRs, P2-layout pre ----------------
__global__ __launch_bounds__(512) void lstm_mfma2(
    const ushort_t* __restrict__ P2,
    const float* __restrict__ Whh,
    float* __restrict__ lstm_out)
{
  const int tid = threadIdx.x, lane = tid & 63, w = tid >> 6;
  const int lr = lane & 15, lkq = lane >> 4;
  __shared__ ushort_t H[2][16 * HSTR];
  {
    ushort_t* hp = &H[0][0];
    for (int i = tid; i < 2*16*HSTR; i += 512) hp[i] = 0;
  }

  bf16x8 bw0[4], bw1[4], bw2[4], bw3[4];
  #pragma unroll
  for (int kk = 0; kk < 4; ++kk) {
    short s[8];
    const float* wp0 = Whh + (long)(0*128 + w*16 + lr) * 128 + kk*32 + lkq*8;
    const float* wp1 = Whh + (long)(1*128 + w*16 + lr) * 128 + kk*32 + lkq*8;
    const float* wp2 = Whh + (long)(2*128 + w*16 + lr) * 128 + kk*32 + lkq*8;
    const float* wp3 = Whh + (long)(3*128 + w*16 + lr) * 128 + kk*32 + lkq*8;
    #pragma unroll
    for (int j = 0; j < 8; ++j) s[j] = (short)f2b(wp0[j]);
    bw0[kk] = bf16x8{s[0],s[1],s[2],s[3],s[4],s[5],s[6],s[7]};
    #pragma unroll
    for (int j = 0; j < 8; ++j) s[j] = (short)f2b(wp1[j]);
    bw1[kk] = bf16x8{s[0],s[1],s[2],s[3],s[4],s[5],s[6],s[7]};
    #pragma unroll
    for (int j = 0; j < 8; ++j) s[j] = (short)f2b(wp2[j]);
    bw2[kk] = bf16x8{s[0],s[1],s[2],s[3],s[4],s[5],s[6],s[7]};
    #pragma unroll
    for (int j = 0; j < 8; ++j) s[j] = (short)f2b(wp3[j]);
    bw3[kk] = bf16x8{s[0],s[1],s[2],s[3],s[4],s[5],s[6],s[7]};
  }

  auto pptr = [&](int t, int q){
    return reinterpret_cast<const uint2*>(P2 + (((((long)t*4 + q)*8 + w)*4 + lkq)*64 + lr*4));
  };
  uint2 pc0 = *pptr(0,0), pc1 = *pptr(0,1), pc2 = *pptr(0,2), pc3 = *pptr(0,3);
  uint2 pn0, pn1, pn2, pn3;
  f32x4 c = {0.f,0.f,0.f,0.f};
  __syncthreads();

  int pb = 0;
  for (int t = 0; t < CT; ++t) {
    if (t + 1 < CT) { pn0 = *pptr(t+1,0); pn1 = *pptr(t+1,1); pn2 = *pptr(t+1,2); pn3 = *pptr(t+1,3); }
    bf16x8 a[4];
    #pragma unroll
    for (int kk = 0; kk < 4; ++kk)
      a[kk] = *reinterpret_cast<const bf16x8*>(&H[pb][lr*HSTR + kk*32 + lkq*8]);
    f32x4 acc0 = f32x4{ b2f(pc0.x & 0xffffu), b2f(pc0.x >> 16), b2f(pc0.y & 0xffffu), b2f(pc0.y >> 16) };
    f32x4 acc1 = f32x4{ b2f(pc1.x & 0xffffu), b2f(pc1.x >> 16), b2f(pc1.y & 0xffffu), b2f(pc1.y >> 16) };
    f32x4 acc2 = f32x4{ b2f(pc2.x & 0xffffu), b2f(pc2.x >> 16), b2f(pc2.y & 0xffffu), b2f(pc2.y >> 16) };
    f32x4 acc3 = f32x4{ b2f(pc3.x & 0xffffu), b2f(pc3.x >> 16), b2f(pc3.y & 0xffffu), b2f(pc3.y >> 16) };
    #pragma unroll
    for (int kk = 0; kk < 4; ++kk) {
      acc0 = __builtin_amdgcn_mfma_f32_16x16x32_bf16(a[kk], bw0[kk], acc0, 0,0,0);
      acc1 = __builtin_amdgcn_mfma_f32_16x16x32_bf16(a[kk], bw1[kk], acc1, 0,0,0);
      acc2 = __builtin_amdgcn_mfma_f32_16x16x32_bf16(a[kk], bw2[kk], acc2, 0,0,0);
      acc3 = __builtin_amdgcn_mfma_f32_16x16x32_bf16(a[kk], bw3[kk], acc3, 0,0,0);
    }
    #pragma unroll
    for (int r = 0; r < 4; ++r) {
      float ig = fsigmoid(acc0[r]);
      float fg = fsigmoid(acc1[r]);
      float gg = ftanh_(acc2[r]);
      float og = fsigmoid(acc3[r]);
      c[r] = fg*c[r] + ig*gg;
      float h = og * ftanh_(c[r]);
      int row = lkq*4 + r;
      H[pb^1][row*HSTR + w*16 + lr] = f2b(h);
      lstm_out[((long)row*CT + t)*128 + w*16 + lr] = h;
    }
    __syncthreads();
    pb ^= 1;
    pc0 = pn0; pc1 = pn1; pc2 = pn2; pc3 = pn3;
  }
}

// ---------------- w: dot over [bert_vec, kc, ia] segments of rnn ----------------
__global__ void w_kernel(const float* __restrict__ rnn, const float* __restrict__ Wt,
                         const float* __restrict__ bt0, float* __restrict__ wbuf)
{
  int bt = blockIdx.x; int lane = threadIdx.x; // 64 threads
  float acc = 0.f;
  for (int i = lane; i < 250; i += 64) {
    float f;
    if (i < 100)      f = rnn[(long)bt*950 + 850 + i];
    else if (i < 150) f = rnn[(long)bt*950 + (i - 100)];
    else              f = rnn[(long)bt*950 + 250 + (i - 150)];
    acc = fmaf(Wt[i], f, acc);
  }
  acc = wredsum(acc);
  if (lane == 0) wbuf[bt] = acc + bt0[0];
}

__global__ void transpose_wfc(const float* __restrict__ Wfc, float* __restrict__ WfcT)
{
  int i = blockIdx.x*256 + threadIdx.x;
  if (i < 100*378) { int o = i / 378, q = i % 378; WfcT[q*100 + o] = Wfc[i]; }
}

// ---------------- final: causal attention + attended + FC + sigmoid ----------------
__global__ __launch_bounds__(256) void final_kernel(
    const float* __restrict__ x, const float* __restrict__ wbuf,
    const float* __restrict__ lstm_out, const float* __restrict__ WfcT,
    const float* __restrict__ bfc, float* __restrict__ out)
{
  int bt = blockIdx.x; int b = bt / CT, i = bt % CT;
  int tid = threadIdx.x;
  __shared__ float p_s[CT];
  __shared__ float feat_s[384];
  if (tid < 64) {
    bool h1 = (64 + tid) < CT;
    float v0 = (tid <= i) ? wbuf[(long)b*CT + tid] : -3.0e38f;
    float v1 = (h1 && (64 + tid) <= i) ? wbuf[(long)b*CT + 64 + tid] : -3.0e38f;
    float mx = wredmax(fmaxf(v0, v1));
    float e0 = (tid <= i) ? __expf(v0 - mx) : 0.f;
    float e1 = (h1 && (64 + tid) <= i) ? __expf(v1 - mx) : 0.f;
    float s = wredsum(e0 + e1);
    float inv = frcp(s);
    p_s[tid] = e0 * inv;
    if (h1) p_s[64 + tid] = e1 * inv;
  }
  __syncthreads();
  if (tid < CHID) {
    float cur = 0.f;
    #pragma unroll 4
    for (int j = 0; j <= i; ++j) cur = fmaf(p_s[j], lstm_out[((long)b*CT + j)*CHID + tid], cur);
    float l = lstm_out[((long)b*CT + i)*CHID + tid];
    float att;
    if (i == 0) att = l;
    else { att = 0.5f * l; if (i <= CT - 2) att = fmaf(0.5f, cur, att); }
    feat_s[250 + tid] = att;
  }
  for (int q = tid; q < 250; q += 256)
    feat_s[q] = (q < 200) ? x[(long)bt*XCH + q] : x[(long)bt*XCH + 1280 + (q - 200)];
  __syncthreads();
  if (tid < 100) {
    float acc = bfc[tid];
    #pragma unroll 4
    for (int q = 0; q < 378; ++q) acc = fmaf(WfcT[q*100 + tid], feat_s[q], acc);
    out[(long)bt*100 + tid] = fsigmoid(acc);
  }
}

extern "C" void kernel_launch(void* const* d_in, const int* in_sizes, int n_in,
                              void* d_out, int out_size, void* d_ws, size_t ws_size,
                              hipStream_t stream) {
  (void)in_sizes; (void)n_in; (void)out_size; (void)ws_size;
  const float* x        = (const float*)d_in[0];
  const float* node_emb = (const float*)d_in[1];
  const float* path_emb = (const float*)d_in[2];
  const float* Wb       = (const float*)d_in[3];
  const float* bb       = (const float*)d_in[4];
  const float* Wna      = (const float*)d_in[5];
  const float* bna      = (const float*)d_in[6];
  const float* Wia      = (const float*)d_in[7];
  const float* bia      = (const float*)d_in[8];
  const float* Wattn    = (const float*)d_in[9];
  const float* battn    = (const float*)d_in[10];
  const float* kc_emb   = (const float*)d_in[11];
  const float* Wt       = (const float*)d_in[12];
  const float* bt0      = (const float*)d_in[13];
  const float* Wih      = (const float*)d_in[14];
  const float* Whh      = (const float*)d_in[15];
  const float* bih      = (const float*)d_in[16];
  const float* bhh      = (const float*)d_in[17];
  const float* Wfc      = (const float*)d_in[18];
  const float* bfc      = (const float*)d_in[19];
  float* out = (float*)d_out;

  char* cur = (char*)d_ws;
  auto alloc = [&](size_t bytes)->char* {
    char* p = cur; cur += (bytes + 255) & ~(size_t)255; return p;
  };
  ushort_t* NODE_ALL = (ushort_t*)alloc((size_t)NNODE*NODE_W*2);   // 28.2 MB
  ushort_t* PATH_ALL = (ushort_t*)alloc((size_t)NPATH*PATH_W*2);   // 30.7 MB
  ushort_t* XR   = (ushort_t*)alloc((size_t)NBT*XR_W*2);
  float* Bn     = (float*)alloc((size_t)NODE_W*100*4);
  float* Bp     = (float*)alloc((size_t)PATH_W*100*4);
  float* Bx     = (float*)alloc((size_t)XR_W*200*4);
  float* bias_x = (float*)alloc((size_t)XR_W*4);
  ushort_t* WAB = (ushort_t*)alloc(512*2);
  float* cwT  = (float*)alloc((size_t)NBT*100*4);
  float* awT  = (float*)alloc((size_t)NBT*100*4);
  float* rnn  = (float*)alloc((size_t)NBT*950*4);
  ushort_t* P2 = (ushort_t*)alloc((size_t)NBT*512*2);
  float* lstm = (float*)alloc((size_t)NBT*128*4);
  float* wbuf = (float*)alloc((size_t)NBT*4);
  float* WfcT = (float*)alloc((size_t)378*100*4);

  // B packs
  pack_Bn<<<(NODE_W*100+255)/256, 256, 0, stream>>>(Wna, Wia, Bn);
  pack_Bp<<<(PATH_W*100+255)/256, 256, 0, stream>>>(Wna, Wia, Bp);
  pack_Bx<<<(XR_W*200+255)/256, 256, 0, stream>>>(Wna, Wia, bna, bia, Bx, bias_x);
  pack_wattn<<<2, 256, 0, stream>>>(Wattn, WAB);

  // table GEMMs: whole-K, merged outputs, XCD-aware grid
  {
    int ncb_n = NODE_W/128, nrb_n = ((NNODE+127)/128 + 7) & ~7;   // 11, 80
    tblgemm<<<ncb_n*nrb_n, 256, 0, stream>>>(node_emb, NNODE, Bn, NODE_W, NODE_ALL);
    int ncb_p = PATH_W/128, nrb_p = ((NPATH+127)/128 + 7) & ~7;   // 6, 160
    tblgemm<<<ncb_p*nrb_p, 256, 0, stream>>>(path_emb, NPATH, Bp, PATH_W, PATH_ALL);
  }
  // XR = x[:, :200] @ Bx^T + bias_x  (R|RW merged, bf16)
  {
    int ncb = (XR_W+63)/64, nrb = (((NBT+127)/128)+7) & ~7;   // 10, 16
    gemm_mfma<1><<<ncb*nrb, 256, 0, stream>>>(x,1330, Bx,200, XR, XR_W, NBT, XR_W, XR_W, 200, bias_x, nullptr, ncb);
  }
  // bert_vec -> rnn[850:950] f32
  {
    int ncb = (100+63)/64, nrb = (((NBT+127)/128)+7) & ~7;    // 2, 16
    gemm_mfma<0><<<ncb*nrb, 256, 0, stream>>>(x+500,1330, Wb,768, rnn+850, 950, NBT,100,100,768, bb, nullptr, ncb);
  }

  cw2_kernel<<<NBT,256,0,stream>>>(x, NODE_ALL, PATH_ALL, XR, WAB, battn, cwT);
  aw_kernel<<<CB*CMCL,64,0,stream>>>(cwT, awT);
  fuse2_kernel<<<NBT,256,0,stream>>>(x, NODE_ALL, PATH_ALL, XR, awT, kc_emb, rnn);

  // LSTM pre-activations (P2 fragment layout) + MFMA recurrence
  {
    int ncb = 512/64, nrb = (((NBT+127)/128)+7) & ~7;         // 8, 16
    gemm_mfma<2><<<ncb*nrb, 256, 0, stream>>>(rnn,950, Wih,950, P2, 0, NBT,512,512,950, bih, bhh, ncb);
  }
  lstm_mfma2<<<1,512,0,stream>>>(P2, Whh, lstm);

  w_kernel<<<NBT,64,0,stream>>>(rnn, Wt, bt0, wbuf);
  transpose_wfc<<<(100*378+255)/256,256,0,stream>>>(Wfc, WfcT);
  final_kernel<<<NBT,256,0,stream>>>(x, wbuf, lstm, WfcT, bfc, out);
}

// Round 7
// 496.088 us; speedup vs baseline: 2.4182x; 1.3117x over previous
//
#include <hip/hip_runtime.h>
#include <math.h>

typedef unsigned short ushort_t;
typedef __attribute__((ext_vector_type(8))) short bf16x8;
typedef __attribute__((ext_vector_type(4))) float f32x4;

// Problem constants
constexpr int CB = 16, CT = 100, CMCL = 100, CDIN = 200;
constexpr int CKC = 50, CHID = 128;
constexpr int XCH = 1330;
constexpr int NBT = CB * CT;       // 1600
constexpr int NNODE = 10002, NPATH = 20002;
constexpr int TRS = 114;           // tr_s ushort stride: 57 dwords, odd -> conflict-free
constexpr int HSTR = 136;          // lstm H row stride (ushorts)
constexpr int NODE_W = 1408;       // [T0A 512|T0C 512|emb 112|Ua 112|Uc 112|pad]
constexpr int PATH_W = 768;        // [TPP 512|emb 112|Up 112|pad]
constexpr int XR_W   = 640;        // [R 512|RW 112|pad]

__device__ __forceinline__ float frcp(float v){ return __builtin_amdgcn_rcpf(v); }
__device__ __forceinline__ float fsigmoid(float v){ return frcp(1.f + __expf(-v)); }
__device__ __forceinline__ float ftanh_(float v){
  float e = __expf(-2.f*fabsf(v));
  return copysignf((1.f - e) * frcp(1.f + e), v);
}
__device__ __forceinline__ float wredsum(float v){
  #pragma unroll
  for (int off = 32; off; off >>= 1) v += __shfl_xor(v, off);
  return v;
}
__device__ __forceinline__ float wredmax(float v){
  #pragma unroll
  for (int off = 32; off; off >>= 1) v = fmaxf(v, __shfl_xor(v, off));
  return v;
}
__device__ __forceinline__ ushort_t f2b(float f){
  union { float f; unsigned u; } c{f};
  return (ushort_t)((c.u + 0x7FFFu + ((c.u >> 16) & 1u)) >> 16);
}
__device__ __forceinline__ float b2f(unsigned hbits){
  union { unsigned u; float f; } c{hbits << 16};
  return c.f;
}
__device__ __forceinline__ void b8f(const ushort_t* p, float* o){
  uint4 v = *reinterpret_cast<const uint4*>(p);
  o[0]=b2f(v.x & 0xFFFFu); o[1]=b2f(v.x >> 16);
  o[2]=b2f(v.y & 0xFFFFu); o[3]=b2f(v.y >> 16);
  o[4]=b2f(v.z & 0xFFFFu); o[5]=b2f(v.z >> 16);
  o[6]=b2f(v.w & 0xFFFFu); o[7]=b2f(v.w >> 16);
}

// ---------------- mega GEMM: multiple sub-GEMMs, whole-K (<=128) staged, optional split-K ----------------
struct GDesc {
  const float* A; const float* B; float* Cf; ushort_t* Cb;
  int lda, kOff, kMax, K, M, Npad, rbp, cb, nsplit, ldc, blocks;
};
struct MegaArgs { GDesc d[4]; int nd; };

__global__ __launch_bounds__(256) void mega_gemm(MegaArgs args)
{
  constexpr int KS = 136;
  __shared__ ushort_t As[128*KS];
  __shared__ ushort_t Bs[128*KS];
  int id = blockIdx.x;
  int di = 0;
  while (di < args.nd-1 && id >= args.d[di].blocks) { id -= args.d[di].blocks; ++di; }
  GDesc g = args.d[di];
  const int per = g.rbp * g.cb;
  const int sp = id / per, r = id % per;
  const int xcd = r & 7, s2 = r >> 3;
  const int y = xcd + 8*(s2 / g.cb), cbi = s2 % g.cb;
  const int bm = y*128, bn = cbi*128;
  if (bm >= g.M) return;
  const int tid = threadIdx.x, lane = tid & 63, w = tid >> 6;
  const int wm = w & 1, wn = w >> 1;
  const int lr = lane & 15, lkq = lane >> 4;
  const int kbase = g.kOff + sp * g.K;
  const int hK = g.K >> 1;

  for (int f = tid; f < 128*hK; f += 256) {
    int row = f / hK, j2 = (f % hK)*2;
    int gm = bm + row;
    float2 va = make_float2(0.f,0.f);
    if (gm < g.M && kbase + j2 + 2 <= g.kMax)
      va = *reinterpret_cast<const float2*>(g.A + (long)gm*g.lda + kbase + j2);
    *reinterpret_cast<unsigned*>(&As[row*KS + j2]) = (unsigned)f2b(va.x) | ((unsigned)f2b(va.y)<<16);
    float2 vb = *reinterpret_cast<const float2*>(g.B + ((long)sp*g.Npad + bn + row)*g.K + j2);
    *reinterpret_cast<unsigned*>(&Bs[row*KS + j2]) = (unsigned)f2b(vb.x) | ((unsigned)f2b(vb.y)<<16);
  }
  const int padw = (128 - g.K) >> 1;   // zero [K,128) dword pairs for MFMA
  for (int f = tid; f < 128*padw; f += 256) {
    int row = f / padw, jd = f % padw;
    *reinterpret_cast<unsigned*>(&As[row*KS + g.K + jd*2]) = 0u;
    *reinterpret_cast<unsigned*>(&Bs[row*KS + g.K + jd*2]) = 0u;
  }
  __syncthreads();

  f32x4 acc[4][4];
  #pragma unroll
  for (int i = 0; i < 4; ++i)
    #pragma unroll
    for (int j = 0; j < 4; ++j) acc[i][j] = f32x4{0.f,0.f,0.f,0.f};
  #pragma unroll
  for (int ks = 0; ks < 4; ++ks) {
    const int ko = ks*32 + lkq*8;
    bf16x8 af[4], bf[4];
    #pragma unroll
    for (int i = 0; i < 4; ++i)
      af[i] = *reinterpret_cast<const bf16x8*>(&As[(wm*64 + i*16 + lr)*KS + ko]);
    #pragma unroll
    for (int j = 0; j < 4; ++j)
      bf[j] = *reinterpret_cast<const bf16x8*>(&Bs[(wn*64 + j*16 + lr)*KS + ko]);
    #pragma unroll
    for (int i = 0; i < 4; ++i)
      #pragma unroll
      for (int j = 0; j < 4; ++j)
        acc[i][j] = __builtin_amdgcn_mfma_f32_16x16x32_bf16(af[i], bf[j], acc[i][j], 0, 0, 0);
  }
  #pragma unroll
  for (int i = 0; i < 4; ++i) {
    #pragma unroll
    for (int j = 0; j < 4; ++j) {
      #pragma unroll
      for (int rr = 0; rr < 4; ++rr) {
        int gr = bm + wm*64 + i*16 + lkq*4 + rr;
        int gc = bn + wn*64 + j*16 + lr;
        if (gr < g.M) {
          if (g.Cb) g.Cb[(long)gr * g.ldc + gc] = f2b(acc[i][j][rr]);
          else      g.Cf[((long)sp*g.M + gr)*g.ldc + gc] = acc[i][j][rr];
        }
      }
    }
  }
}

// ---------------- B-pack kernels ----------------
__global__ void pack_Bn(const float* __restrict__ Wna, const float* __restrict__ Wia, float* __restrict__ Bn)
{
  int i = blockIdx.x*256 + threadIdx.x;
  if (i >= NODE_W*100) return;
  int n = i / 100, k = i % 100;
  float v = 0.f;
  if (n < 500)                      v = Wna[(long)n*500 + k];
  else if (n >= 512 && n < 1012)    v = Wna[(long)(n-512)*500 + 100 + k];
  else if (n >= 1024 && n < 1124)   v = (k == n-1024) ? 1.f : 0.f;
  else if (n >= 1136 && n < 1236)   v = Wia[(long)(n-1136)*500 + k];
  else if (n >= 1248 && n < 1348)   v = Wia[(long)(n-1248)*500 + 100 + k];
  Bn[i] = v;
}
__global__ void pack_Bp(const float* __restrict__ Wna, const float* __restrict__ Wia, float* __restrict__ Bp)
{
  int i = blockIdx.x*256 + threadIdx.x;
  if (i >= PATH_W*100) return;
  int n = i / 100, k = i % 100;
  float v = 0.f;
  if (n < 500)                    v = Wna[(long)n*500 + 200 + k];
  else if (n >= 512 && n < 612)   v = (k == n-512) ? 1.f : 0.f;
  else if (n >= 624 && n < 724)   v = Wia[(long)(n-624)*500 + 200 + k];
  Bp[i] = v;
}
__global__ void pack_XB2(const float* __restrict__ Wna, const float* __restrict__ Wia,
                         const float* __restrict__ bna, const float* __restrict__ bia,
                         float* __restrict__ XB2, float* __restrict__ bias_x)
{
  int i = blockIdx.x*256 + threadIdx.x;
  if (i < XR_W) {
    float b = 0.f;
    if (i < 500) b = bna[i];
    else if (i >= 512 && i < 612) b = bia[i-512];
    bias_x[i] = b;
  }
  if (i >= 2*XR_W*100) return;
  int s = i / (XR_W*100), n = (i / 100) % XR_W, k = i % 100;
  int k2 = s*100 + k;
  float v = 0.f;
  if (n < 500)                  v = Wna[(long)n*500 + 300 + k2];
  else if (n >= 512 && n < 612) v = Wia[(long)(n-512)*500 + 300 + k2];
  XB2[i] = v;
}
__global__ void pack_bertB(const float* __restrict__ Wb, float* __restrict__ BertB)
{
  int i = blockIdx.x*256 + threadIdx.x;
  if (i >= 6*128*128) return;
  int s = i / (128*128), n = (i / 128) % 128, k = i % 128;
  BertB[i] = (n < 100) ? Wb[(long)n*768 + s*128 + k] : 0.f;
}
__global__ void pack_P2B(const float* __restrict__ Wih, float* __restrict__ P2B)
{
  int i = blockIdx.x*256 + threadIdx.x;
  if (i >= 10*512*96) return;
  int s = i / (512*96), n = (i / 96) % 512, k = i % 96;
  int kg = s*96 + k;
  P2B[i] = (kg < 950) ? Wih[(long)n*950 + kg] : 0.f;
}
__global__ void pack_wattn(const float* __restrict__ Wattn, ushort_t* __restrict__ wab)
{
  int i = blockIdx.x * 256 + threadIdx.x;
  if (i < 512) wab[i] = (i < 500) ? f2b(Wattn[i]) : (ushort_t)0;
}

// ---------------- reduce1: XR (2 splits + bias -> bf16) and bert (6 splits + bias -> rnn f32) ----------------
__global__ __launch_bounds__(256) void reduce1(
    const float* __restrict__ xrP, const float* __restrict__ bias_x, ushort_t* __restrict__ XR,
    const float* __restrict__ bertP, const float* __restrict__ bb, float* __restrict__ rnn)
{
  int bt = blockIdx.x, tid = threadIdx.x;
  for (int c = tid; c < XR_W; c += 256) {
    float v = xrP[(long)bt*XR_W + c] + xrP[((long)NBT + bt)*XR_W + c] + bias_x[c];
    XR[(long)bt*XR_W + c] = f2b(v);
  }
  if (tid < 100) {
    float v = bb[tid];
    #pragma unroll
    for (int s = 0; s < 6; ++s) v += bertP[((long)s*NBT + bt)*128 + tid];
    rnn[(long)bt*950 + 850 + tid] = v;
  }
}

// ---------------- reduce_p2: 10 splits + biases -> P2 fragment-layout bf16 ----------------
__global__ __launch_bounds__(512) void reduce_p2(
    const float* __restrict__ p2P, const float* __restrict__ bih, const float* __restrict__ bhh,
    ushort_t* __restrict__ P2)
{
  int bt = blockIdx.x, g = threadIdx.x;
  float v = bih[g] + bhh[g];
  #pragma unroll
  for (int s = 0; s < 10; ++s) v += p2P[((long)s*NBT + bt)*512 + g];
  int bq = bt / CT, tt = bt % CT;
  int q = g >> 7, rem = g & 127, ww = rem >> 4, lr2 = rem & 15;
  int lk2 = bq >> 2, rr = bq & 3;
  P2[((((long)tt*4 + q)*8 + ww)*4 + lk2)*64 + lr2*4 + rr] = f2b(v);
}

// ---------------- cw: per (b,t), all m: Wattn . tanh(T0A[a]+T0C[c]+TPP[p]+R) ----------------
__global__ __launch_bounds__(256) void cw2_kernel(
    const float* __restrict__ x, const ushort_t* __restrict__ NODE_ALL,
    const ushort_t* __restrict__ PATH_ALL, const ushort_t* __restrict__ XR,
    const ushort_t* __restrict__ WAB,
    const float* __restrict__ battn, float* __restrict__ cwT)
{
  int bt = blockIdx.x, b = bt / CT, t = bt % CT;
  int tid = threadIdx.x, w = tid >> 6, lane = tid & 63;
  __shared__ int idx_s[300];
  for (int i = tid; i < 300; i += 256) idx_s[i] = (int)x[(long)bt*XCH + 200 + i];
  float rseg[8], wseg[8];
  b8f(XR + (long)bt*XR_W + lane*8, rseg);
  b8f(WAB + lane*8, wseg);
  __syncthreads();
  float bat = battn[0];

  uint4 A0, C0, P0, A1, C1, P1;
  auto issue = [&](int m, uint4& A, uint4& C, uint4& P){
    if (m < CMCL) {
      int ai = idx_s[3*m], pi = idx_s[3*m+1], ci = idx_s[3*m+2];
      A = *reinterpret_cast<const uint4*>(NODE_ALL + (long)ai*NODE_W + lane*8);
      C = *reinterpret_cast<const uint4*>(NODE_ALL + (long)ci*NODE_W + 512 + lane*8);
      P = *reinterpret_cast<const uint4*>(PATH_ALL + (long)pi*PATH_W + lane*8);
    }
  };
  auto proc = [&](int m, const uint4& A, const uint4& C, const uint4& P){
    if (m >= CMCL) return;
    const unsigned ua[4] = {A.x, A.y, A.z, A.w};
    const unsigned uc[4] = {C.x, C.y, C.z, C.w};
    const unsigned up[4] = {P.x, P.y, P.z, P.w};
    float acc = 0.f;
    #pragma unroll
    for (int jj = 0; jj < 4; ++jj) {
      float lo = b2f(ua[jj] & 0xffffu) + b2f(uc[jj] & 0xffffu) + b2f(up[jj] & 0xffffu) + rseg[2*jj];
      float hi = b2f(ua[jj] >> 16)     + b2f(uc[jj] >> 16)     + b2f(up[jj] >> 16)     + rseg[2*jj+1];
      acc = fmaf(ftanh_(lo), wseg[2*jj], acc);
      acc = fmaf(ftanh_(hi), wseg[2*jj+1], acc);
    }
    acc = wredsum(acc);
    if (lane == 0) cwT[((long)b*CMCL + m)*CT + t] = acc + bat;
  };

  issue(w, A0, C0, P0);
  for (int it = 0; it < 25; it += 2) {
    int m0 = w + it*4;
    issue(m0 + 4, A1, C1, P1);
    proc(m0, A0, C0, P0);
    issue(m0 + 8, A0, C0, P0);
    proc(m0 + 4, A1, C1, P1);
  }
}

// ---------------- aw: softmax over t for each (b,m) ----------------
__global__ void aw_kernel(const float* __restrict__ cwT, float* __restrict__ awT)
{
  int bm = blockIdx.x; int lane = threadIdx.x;   // 64 threads
  const float* row = cwT + (long)bm * CT;
  bool h1 = lane < (CT - 64);
  float v0 = row[lane];
  float v1 = h1 ? row[64 + lane] : -3.0e38f;
  float mx = wredmax(fmaxf(v0, v1));
  float e0 = __expf(v0 - mx);
  float e1 = h1 ? __expf(v1 - mx) : 0.f;
  float s = wredsum(e0 + e1);
  float inv = frcp(s);
  awT[(long)bm*CT + lane] = e0 * inv;
  if (h1) awT[(long)bm*CT + 64 + lane] = e1 * inv;
}

// ---------------- fused: na + trans(LDS bf16) + kc-attention -> rnn[0:850] ----------------
__global__ __launch_bounds__(256) void fuse2_kernel(
    const float* __restrict__ x,
    const ushort_t* __restrict__ NODE_ALL, const ushort_t* __restrict__ PATH_ALL,
    const ushort_t* __restrict__ XR, const float* __restrict__ awT,
    const float* __restrict__ kc_emb, float* __restrict__ rnn)
{
  int bt = blockIdx.x, b = bt / CT, t = bt % CT;
  int tid = threadIdx.x, w = tid >> 6, lane = tid & 63;
  int sub = lane >> 5, li = lane & 31;

  __shared__ ushort_t tr_s[100*TRS];
  __shared__ float nacc[4][344];
  __shared__ float ia_red[4][104];
  __shared__ float aw_s[100];
  __shared__ int   idx_s[300];
  __shared__ float kcl[CKC];
  __shared__ int   act_k[CKC];
  __shared__ int   nact_s;
  __shared__ float kcn_s, awsum_s;

  for (int i = tid; i < 300; i += 256) idx_s[i] = (int)x[(long)bt*XCH + 200 + i];
  if (tid < 100) aw_s[tid] = awT[((long)b*CMCL + tid)*CT + t];
  if (tid < CKC) kcl[tid] = x[(long)bt*XCH + 1280 + tid];
  __syncthreads();
  if (tid == 0) {
    float kcn = 0.f; int na = 0;
    for (int k = 0; k < CKC; ++k) { float v = kcl[k]; kcn += v; if (v != 0.f) act_k[na++] = k; }
    nact_s = na; kcn_s = (kcn == 0.f) ? 1.f : kcn;
    float s = 0.f;
    for (int m = 0; m < CMCL; ++m) s += aw_s[m];
    awsum_s = s;
  }
  float rwseg[8];
  if (li >= 14 && li < 28) b8f(XR + (long)bt*XR_W + 512 + (li-14)*8, rwseg);
  __syncthreads();

  // ---- gather phase ----
  float na_a[8] = {}, na_c[8] = {}, na_p[8] = {};
  const bool gv = (li < 28);
  uint4 A0, C0, P0, A1, C1, P1;
  auto g_issue = [&](int m, uint4& A, uint4& C, uint4& P){
    if (m < CMCL && gv) {
      int ai = idx_s[3*m], pi = idx_s[3*m+1], ci = idx_s[3*m+2];
      int eo = li*8, uo = (li-14)*8;
      A = *reinterpret_cast<const uint4*>(NODE_ALL + (long)ai*NODE_W + 1024 + eo);
      C = *reinterpret_cast<const uint4*>(NODE_ALL + (long)ci*NODE_W + ((li<14) ? 1024 + eo : 1248 + uo));
      P = *reinterpret_cast<const uint4*>(PATH_ALL + (long)pi*PATH_W + 512 + eo);
    }
  };
  auto g_proc = [&](int m, const uint4& A, const uint4& C, const uint4& P){
    if (m >= CMCL || !gv) return;
    const unsigned ua[4] = {A.x, A.y, A.z, A.w};
    const unsigned uc[4] = {C.x, C.y, C.z, C.w};
    const unsigned up[4] = {P.x, P.y, P.z, P.w};
    if (li < 14) {
      float awm = aw_s[m];
      #pragma unroll
      for (int jj = 0; jj < 4; ++jj) {
        na_a[2*jj]   = fmaf(awm, b2f(ua[jj] & 0xffffu), na_a[2*jj]);
        na_a[2*jj+1] = fmaf(awm, b2f(ua[jj] >> 16),     na_a[2*jj+1]);
        na_c[2*jj]   = fmaf(awm, b2f(uc[jj] & 0xffffu), na_c[2*jj]);
        na_c[2*jj+1] = fmaf(awm, b2f(uc[jj] >> 16),     na_c[2*jj+1]);
        na_p[2*jj]   = fmaf(awm, b2f(up[jj] & 0xffffu), na_p[2*jj]);
        na_p[2*jj+1] = fmaf(awm, b2f(up[jj] >> 16),     na_p[2*jj+1]);
      }
    } else {
      unsigned* d32 = reinterpret_cast<unsigned*>(&tr_s[m*TRS + (li-14)*8]);
      #pragma unroll
      for (int jj = 0; jj < 4; ++jj) {
        float lo = b2f(ua[jj] & 0xffffu) + b2f(uc[jj] & 0xffffu) + b2f(up[jj] & 0xffffu) + rwseg[2*jj];
        float hi = b2f(ua[jj] >> 16)     + b2f(uc[jj] >> 16)     + b2f(up[jj] >> 16)     + rwseg[2*jj+1];
        d32[jj] = (unsigned)f2b(lo) | ((unsigned)f2b(hi) << 16);
      }
    }
  };
  const int mb = w*2 + sub;
  g_issue(mb, A0, C0, P0);
  for (int it = 0; it < 13; it += 2) {
    g_issue((it+1)*8 + mb, A1, C1, P1);
    g_proc(it*8 + mb, A0, C0, P0);
    g_issue((it+2)*8 + mb, A0, C0, P0);
    g_proc((it+1)*8 + mb, A1, C1, P1);
  }
  #pragma unroll
  for (int j = 0; j < 8; ++j) {
    na_a[j] += __shfl_xor(na_a[j], 32);
    na_c[j] += __shfl_xor(na_c[j], 32);
    na_p[j] += __shfl_xor(na_p[j], 32);
  }
  if (lane < 14) {
    #pragma unroll
    for (int j = 0; j < 8; ++j) {
      nacc[w][      lane*8 + j] = na_a[j];
      nacc[w][112 + lane*8 + j] = na_c[j];
      nacc[w][224 + lane*8 + j] = na_p[j];
    }
  }
  __syncthreads();

  for (int q = tid; q < 336; q += 256) {
    float v = nacc[0][q] + nacc[1][q] + nacc[2][q] + nacc[3][q];
    int seg = q / 112, col = q % 112;
    if (col < 100) rnn[(long)bt*950 + 350 + seg*100 + col] = v;
  }
  for (int q = tid; q < CDIN; q += 256) {
    float xv = x[(long)bt*XCH + q];
    rnn[(long)bt*950 + 50 + q] = xv;
    rnn[(long)bt*950 + 650 + q] = awsum_s * xv;
  }
  if (tid < CKC) rnn[(long)bt*950 + tid] = kcl[tid];

  // ---- kc attention ----
  float ia0 = 0.f, ia1 = 0.f;
  const bool vrow1 = lane < 36;
  const bool vpv   = lane < 50;
  const int nact = nact_s;
  const unsigned* tr32_0 = reinterpret_cast<const unsigned*>(&tr_s[lane*TRS]);
  const unsigned* tr32_1 = reinterpret_cast<const unsigned*>(&tr_s[(64+lane)*TRS]);
  const unsigned* tr32   = reinterpret_cast<const unsigned*>(tr_s);
  for (int ki = w; ki < nact; ki += 4) {
    int k = act_k[ki];
    float kck = kcl[k];
    const float* ke = kc_emb + (long)k*100;
    float s0 = 0.f, s1 = 0.f;
    #pragma unroll 5
    for (int dh = 0; dh < 50; ++dh) {
      float k0 = ke[2*dh], k1 = ke[2*dh+1];
      unsigned u0 = tr32_0[dh];
      s0 = fmaf(k0, b2f(u0 & 0xffffu), s0);
      s0 = fmaf(k1, b2f(u0 >> 16), s0);
      if (vrow1) {
        unsigned u1 = tr32_1[dh];
        s1 = fmaf(k0, b2f(u1 & 0xffffu), s1);
        s1 = fmaf(k1, b2f(u1 >> 16), s1);
      }
    }
    s0 *= kck; s1 *= kck;
    float mx = wredmax(fmaxf(s0, vrow1 ? s1 : -3.0e38f));
    float p0e = __expf(s0 - mx);
    float p1e = vrow1 ? __expf(s1 - mx) : 0.f;
    float sm = wredsum(p0e + p1e);
    float inv = kck * frcp(sm);
    p0e *= inv; p1e *= inv;
    #pragma unroll 4
    for (int m = 0; m < CMCL; ++m) {
      float pm = (m < 64) ? __shfl(p0e, m) : __shfl(p1e, m - 64);
      if (vpv) {
        unsigned u = tr32[m*57 + lane];
        ia0 = fmaf(pm, b2f(u & 0xffffu), ia0);
        ia1 = fmaf(pm, b2f(u >> 16), ia1);
      }
    }
  }
  if (vpv) { ia_red[w][2*lane] = ia0; ia_red[w][2*lane+1] = ia1; }
  __syncthreads();
  if (tid < 100) {
    float v = (ia_red[0][tid] + ia_red[1][tid] + ia_red[2][tid] + ia_red[3][tid]) * frcp(kcn_s);
    rnn[(long)bt*950 + 250 + tid] = v;
  }
}

// ---------------- LSTM via MFMA: 1 block, 16 batches, Whh frags in VGPRs, P2-layout pre ----------------
__global__ __launch_bounds__(512) void lstm_mfma2(
    const ushort_t* __restrict__ P2,
    const float* __restrict__ Whh,
    float* __restrict__ lstm_out)
{
  const int tid = threadIdx.x, lane = tid & 63, w = tid >> 6;
  const int lr = lane & 15, lkq = lane >> 4;
  __shared__ ushort_t H[2][16 * HSTR];
  {
    ushort_t* hp = &H[0][0];
    for (int i = tid; i < 2*16*HSTR; i += 512) hp[i] = 0;
  }

  bf16x8 bw0[4], bw1[4], bw2[4], bw3[4];
  #pragma unroll
  for (int kk = 0; kk < 4; ++kk) {
    short s[8];
    const float* wp0 = Whh + (long)(0*128 + w*16 + lr) * 128 + kk*32 + lkq*8;
    const float* wp1 = Whh + (long)(1*128 + w*16 + lr) * 128 + kk*32 + lkq*8;
    const float* wp2 = Whh + (long)(2*128 + w*16 + lr) * 128 + kk*32 + lkq*8;
    const float* wp3 = Whh + (long)(3*128 + w*16 + lr) * 128 + kk*32 + lkq*8;
    #pragma unroll
    for (int j = 0; j < 8; ++j) s[j] = (short)f2b(wp0[j]);
    bw0[kk] = bf16x8{s[0],s[1],s[2],s[3],s[4],s[5],s[6],s[7]};
    #pragma unroll
    for (int j = 0; j < 8; ++j) s[j] = (short)f2b(wp1[j]);
    bw1[kk] = bf16x8{s[0],s[1],s[2],s[3],s[4],s[5],s[6],s[7]};
    #pragma unroll
    for (int j = 0; j < 8; ++j) s[j] = (short)f2b(wp2[j]);
    bw2[kk] = bf16x8{s[0],s[1],s[2],s[3],s[4],s[5],s[6],s[7]};
    #pragma unroll
    for (int j = 0; j < 8; ++j) s[j] = (short)f2b(wp3[j]);
    bw3[kk] = bf16x8{s[0],s[1],s[2],s[3],s[4],s[5],s[6],s[7]};
  }

  auto pptr = [&](int t, int q){
    return reinterpret_cast<const uint2*>(P2 + (((((long)t*4 + q)*8 + w)*4 + lkq)*64 + lr*4));
  };
  uint2 pc0 = *pptr(0,0), pc1 = *pptr(0,1), pc2 = *pptr(0,2), pc3 = *pptr(0,3);
  uint2 pn0, pn1, pn2, pn3;
  f32x4 c = {0.f,0.f,0.f,0.f};
  __syncthreads();

  int pb = 0;
  for (int t = 0; t < CT; ++t) {
    if (t + 1 < CT) { pn0 = *pptr(t+1,0); pn1 = *pptr(t+1,1); pn2 = *pptr(t+1,2); pn3 = *pptr(t+1,3); }
    bf16x8 a[4];
    #pragma unroll
    for (int kk = 0; kk < 4; ++kk)
      a[kk] = *reinterpret_cast<const bf16x8*>(&H[pb][lr*HSTR + kk*32 + lkq*8]);
    f32x4 acc0 = f32x4{ b2f(pc0.x & 0xffffu), b2f(pc0.x >> 16), b2f(pc0.y & 0xffffu), b2f(pc0.y >> 16) };
    f32x4 acc1 = f32x4{ b2f(pc1.x & 0xffffu), b2f(pc1.x >> 16), b2f(pc1.y & 0xffffu), b2f(pc1.y >> 16) };
    f32x4 acc2 = f32x4{ b2f(pc2.x & 0xffffu), b2f(pc2.x >> 16), b2f(pc2.y & 0xffffu), b2f(pc2.y >> 16) };
    f32x4 acc3 = f32x4{ b2f(pc3.x & 0xffffu), b2f(pc3.x >> 16), b2f(pc3.y & 0xffffu), b2f(pc3.y >> 16) };
    #pragma unroll
    for (int kk = 0; kk < 4; ++kk) {
      acc0 = __builtin_amdgcn_mfma_f32_16x16x32_bf16(a[kk], bw0[kk], acc0, 0,0,0);
      acc1 = __builtin_amdgcn_mfma_f32_16x16x32_bf16(a[kk], bw1[kk], acc1, 0,0,0);
      acc2 = __builtin_amdgcn_mfma_f32_16x16x32_bf16(a[kk], bw2[kk], acc2, 0,0,0);
      acc3 = __builtin_amdgcn_mfma_f32_16x16x32_bf16(a[kk], bw3[kk], acc3, 0,0,0);
    }
    #pragma unroll
    for (int r = 0; r < 4; ++r) {
      float ig = fsigmoid(acc0[r]);
      float fg = fsigmoid(acc1[r]);
      float gg = ftanh_(acc2[r]);
      float og = fsigmoid(acc3[r]);
      c[r] = fg*c[r] + ig*gg;
      float h = og * ftanh_(c[r]);
      int row = lkq*4 + r;
      H[pb^1][row*HSTR + w*16 + lr] = f2b(h);
      lstm_out[((long)row*CT + t)*128 + w*16 + lr] = h;
    }
    __syncthreads();
    pb ^= 1;
    pc0 = pn0; pc1 = pn1; pc2 = pn2; pc3 = pn3;
  }
}

// ---------------- w: dot over [bert_vec, kc, ia] segments of rnn ----------------
__global__ void w_kernel(const float* __restrict__ rnn, const float* __restrict__ Wt,
                         const float* __restrict__ bt0, float* __restrict__ wbuf)
{
  int bt = blockIdx.x; int lane = threadIdx.x; // 64 threads
  float acc = 0.f;
  for (int i = lane; i < 250; i += 64) {
    float f;
    if (i < 100)      f = rnn[(long)bt*950 + 850 + i];
    else if (i < 150) f = rnn[(long)bt*950 + (i - 100)];
    else              f = rnn[(long)bt*950 + 250 + (i - 150)];
    acc = fmaf(Wt[i], f, acc);
  }
  acc = wredsum(acc);
  if (lane == 0) wbuf[bt] = acc + bt0[0];
}

__global__ void transpose_wfc(const float* __restrict__ Wfc, float* __restrict__ WfcT)
{
  int i = blockIdx.x*256 + threadIdx.x;
  if (i < 100*378) { int o = i / 378, q = i % 378; WfcT[q*100 + o] = Wfc[i]; }
}

// ---------------- final: causal attention + attended + FC + sigmoid ----------------
__global__ __launch_bounds__(256) void final_kernel(
    const float* __restrict__ x, const float* __restrict__ wbuf,
    const float* __restrict__ lstm_out, const float* __restrict__ WfcT,
    const float* __restrict__ bfc, float* __restrict__ out)
{
  int bt = blockIdx.x; int b = bt / CT, i = bt % CT;
  int tid = threadIdx.x;
  __shared__ float p_s[CT];
  __shared__ float feat_s[384];
  if (tid < 64) {
    bool h1 = (64 + tid) < CT;
    float v0 = (tid <= i) ? wbuf[(long)b*CT + tid] : -3.0e38f;
    float v1 = (h1 && (64 + tid) <= i) ? wbuf[(long)b*CT + 64 + tid] : -3.0e38f;
    float mx = wredmax(fmaxf(v0, v1));
    float e0 = (tid <= i) ? __expf(v0 - mx) : 0.f;
    float e1 = (h1 && (64 + tid) <= i) ? __expf(v1 - mx) : 0.f;
    float s = wredsum(e0 + e1);
    float inv = frcp(s);
    p_s[tid] = e0 * inv;
    if (h1) p_s[64 + tid] = e1 * inv;
  }
  __syncthreads();
  if (tid < CHID) {
    float cur = 0.f;
    #pragma unroll 4
    for (int j = 0; j <= i; ++j) cur = fmaf(p_s[j], lstm_out[((long)b*CT + j)*CHID + tid], cur);
    float l = lstm_out[((long)b*CT + i)*CHID + tid];
    float att;
    if (i == 0) att = l;
    else { att = 0.5f * l; if (i <= CT - 2) att = fmaf(0.5f, cur, att); }
    feat_s[250 + tid] = att;
  }
  for (int q = tid; q < 250; q += 256)
    feat_s[q] = (q < 200) ? x[(long)bt*XCH + q] : x[(long)bt*XCH + 1280 + (q - 200)];
  __syncthreads();
  if (tid < 100) {
    float acc = bfc[tid];
    #pragma unroll 4
    for (int q = 0; q < 378; ++q) acc = fmaf(WfcT[q*100 + tid], feat_s[q], acc);
    out[(long)bt*100 + tid] = fsigmoid(acc);
  }
}

extern "C" void kernel_launch(void* const* d_in, const int* in_sizes, int n_in,
                              void* d_out, int out_size, void* d_ws, size_t ws_size,
                              hipStream_t stream) {
  (void)in_sizes; (void)n_in; (void)out_size; (void)ws_size;
  const float* x        = (const float*)d_in[0];
  const float* node_emb = (const float*)d_in[1];
  const float* path_emb = (const float*)d_in[2];
  const float* Wb       = (const float*)d_in[3];
  const float* bb       = (const float*)d_in[4];
  const float* Wna      = (const float*)d_in[5];
  const float* bna      = (const float*)d_in[6];
  const float* Wia      = (const float*)d_in[7];
  const float* bia      = (const float*)d_in[8];
  const float* Wattn    = (const float*)d_in[9];
  const float* battn    = (const float*)d_in[10];
  const float* kc_emb   = (const float*)d_in[11];
  const float* Wt       = (const float*)d_in[12];
  const float* bt0      = (const float*)d_in[13];
  const float* Wih      = (const float*)d_in[14];
  const float* Whh      = (const float*)d_in[15];
  const float* bih      = (const float*)d_in[16];
  const float* bhh      = (const float*)d_in[17];
  const float* Wfc      = (const float*)d_in[18];
  const float* bfc      = (const float*)d_in[19];
  float* out = (float*)d_out;

  char* cur = (char*)d_ws;
  auto alloc = [&](size_t bytes)->char* {
    char* p = cur; cur += (bytes + 255) & ~(size_t)255; return p;
  };
  ushort_t* NODE_ALL = (ushort_t*)alloc((size_t)NNODE*NODE_W*2);   // 28.2 MB
  ushort_t* PATH_ALL = (ushort_t*)alloc((size_t)NPATH*PATH_W*2);   // 30.7 MB
  ushort_t* XR   = (ushort_t*)alloc((size_t)NBT*XR_W*2);
  float* Bn     = (float*)alloc((size_t)NODE_W*100*4);
  float* Bp     = (float*)alloc((size_t)PATH_W*100*4);
  float* BertB  = (float*)alloc((size_t)6*128*128*4);
  float* XB2    = (float*)alloc((size_t)2*XR_W*100*4);
  float* P2B    = (float*)alloc((size_t)10*512*96*4);
  float* bias_x = (float*)alloc((size_t)XR_W*4);
  ushort_t* WAB = (ushort_t*)alloc(512*2);
  float* cwT  = (float*)alloc((size_t)NBT*100*4);
  float* awT  = (float*)alloc((size_t)NBT*100*4);
  float* rnn  = (float*)alloc((size_t)NBT*950*4);
  // union region: {xrP | bertP} (13.2 MB) reused later as p2P (32.8 MB)
  char*  uni  = alloc((size_t)10*NBT*512*4);
  float* xrP   = (float*)uni;                                   // 2*1600*640*4 = 8.2 MB
  float* bertP = (float*)(uni + (size_t)2*NBT*XR_W*4);          // 6*1600*128*4 = 4.9 MB
  float* p2P   = (float*)uni;                                   // 10*1600*512*4
  ushort_t* P2 = (ushort_t*)alloc((size_t)NBT*512*2);
  float* lstm = (float*)alloc((size_t)NBT*128*4);
  float* wbuf = (float*)alloc((size_t)NBT*4);
  float* WfcT = (float*)alloc((size_t)378*100*4);

  // ---- packs ----
  pack_Bn<<<(NODE_W*100+255)/256, 256, 0, stream>>>(Wna, Wia, Bn);
  pack_Bp<<<(PATH_W*100+255)/256, 256, 0, stream>>>(Wna, Wia, Bp);
  pack_XB2<<<(2*XR_W*100+255)/256, 256, 0, stream>>>(Wna, Wia, bna, bia, XB2, bias_x);
  pack_bertB<<<(6*128*128+255)/256, 256, 0, stream>>>(Wb, BertB);
  pack_P2B<<<(10*512*96+255)/256, 256, 0, stream>>>(Wih, P2B);
  pack_wattn<<<2, 256, 0, stream>>>(Wattn, WAB);
  transpose_wfc<<<(100*378+255)/256,256,0,stream>>>(Wfc, WfcT);

  // ---- MEGA1: node, path, bert (split-K 6), XR (split-K 2) ----
  {
    MegaArgs a{};
    a.nd = 4;
    // node: M=10002, Npad=1408, K=100
    a.d[0] = { node_emb, Bn, nullptr, NODE_ALL, 100, 0, 100, 100, NNODE, NODE_W, 80, 11, 1, NODE_W, 80*11 };
    // path: M=20002, Npad=768, K=100
    a.d[1] = { path_emb, Bp, nullptr, PATH_ALL, 100, 0, 100, 100, NPATH, PATH_W, 160, 6, 1, PATH_W, 160*6 };
    // bert: A=x cols [500,1268), 6 splits of K=128, partials f32
    a.d[2] = { x, BertB, bertP, nullptr, XCH, 500, 1268, 128, NBT, 128, 16, 1, 6, 128, 16*1*6 };
    // XR: A=x cols [0,200), 2 splits of K=100, partials f32
    a.d[3] = { x, XB2, xrP, nullptr, XCH, 0, 200, 100, NBT, XR_W, 16, 5, 2, XR_W, 16*5*2 };
    int total = a.d[0].blocks + a.d[1].blocks + a.d[2].blocks + a.d[3].blocks;
    mega_gemm<<<total, 256, 0, stream>>>(a);
  }
  reduce1<<<NBT, 256, 0, stream>>>(xrP, bias_x, XR, bertP, bb, rnn);

  cw2_kernel<<<NBT,256,0,stream>>>(x, NODE_ALL, PATH_ALL, XR, WAB, battn, cwT);
  aw_kernel<<<CB*CMCL,64,0,stream>>>(cwT, awT);
  fuse2_kernel<<<NBT,256,0,stream>>>(x, NODE_ALL, PATH_ALL, XR, awT, kc_emb, rnn);

  // ---- MEGA2: P2 pre-activation GEMM (split-K 10) + reduce into fragment layout ----
  {
    MegaArgs a{};
    a.nd = 1;
    a.d[0] = { rnn, P2B, p2P, nullptr, 950, 0, 950, 96, NBT, 512, 16, 4, 10, 512, 16*4*10 };
    mega_gemm<<<a.d[0].blocks, 256, 0, stream>>>(a);
  }
  reduce_p2<<<NBT, 512, 0, stream>>>(p2P, bih, bhh, P2);

  lstm_mfma2<<<1,512,0,stream>>>(P2, Whh, lstm);
  w_kernel<<<NBT,64,0,stream>>>(rnn, Wt, bt0, wbuf);
  final_kernel<<<NBT,256,0,stream>>>(x, wbuf, lstm, WfcT, bfc, out);
}

// Round 8
// 485.738 us; speedup vs baseline: 2.4697x; 1.0213x over previous
//
#include <hip/hip_runtime.h>
#include <math.h>

typedef unsigned short ushort_t;
typedef __attribute__((ext_vector_type(8))) short bf16x8;
typedef __attribute__((ext_vector_type(4))) float f32x4;

// Problem constants
constexpr int CB = 16, CT = 100, CMCL = 100, CDIN = 200;
constexpr int CKC = 50, CHID = 128;
constexpr int XCH = 1330;
constexpr int NBT = CB * CT;       // 1600
constexpr int NNODE = 10002, NPATH = 20002;
constexpr int TRS = 114;           // tr_s ushort stride: 57 dwords, odd -> conflict-free
constexpr int HSTR = 136;          // lstm H row stride (ushorts)
constexpr int NODE_W = 1536;       // [T0A 512|T0C 512|embUa 256|embUc 256] (all 128B-aligned)
constexpr int PATH_W = 768;        // [TPP 512|embUp 256]
constexpr int XR_W   = 640;        // [R 512|RW 112|pad]

__device__ __forceinline__ float frcp(float v){ return __builtin_amdgcn_rcpf(v); }
__device__ __forceinline__ float fsigmoid(float v){ return frcp(1.f + __expf(-v)); }
__device__ __forceinline__ float ftanh_(float v){
  float e = __expf(-2.f*fabsf(v));
  return copysignf((1.f - e) * frcp(1.f + e), v);
}
__device__ __forceinline__ float wredsum(float v){
  #pragma unroll
  for (int off = 32; off; off >>= 1) v += __shfl_xor(v, off);
  return v;
}
__device__ __forceinline__ float wredmax(float v){
  #pragma unroll
  for (int off = 32; off; off >>= 1) v = fmaxf(v, __shfl_xor(v, off));
  return v;
}
__device__ __forceinline__ ushort_t f2b(float f){
  union { float f; unsigned u; } c{f};
  return (ushort_t)((c.u + 0x7FFFu + ((c.u >> 16) & 1u)) >> 16);
}
__device__ __forceinline__ float b2f(unsigned hbits){
  union { unsigned u; float f; } c{hbits << 16};
  return c.f;
}
__device__ __forceinline__ void b8f(const ushort_t* p, float* o){
  uint4 v = *reinterpret_cast<const uint4*>(p);
  o[0]=b2f(v.x & 0xFFFFu); o[1]=b2f(v.x >> 16);
  o[2]=b2f(v.y & 0xFFFFu); o[3]=b2f(v.y >> 16);
  o[4]=b2f(v.z & 0xFFFFu); o[5]=b2f(v.z >> 16);
  o[6]=b2f(v.w & 0xFFFFu); o[7]=b2f(v.w >> 16);
}

// ---------------- mega GEMM: multiple sub-GEMMs, whole-K (<=128) staged, optional split-K ----------------
struct GDesc {
  const float* A; const float* B; float* Cf; ushort_t* Cb;
  int lda, kOff, kMax, K, M, Npad, rbp, cb, nsplit, ldc, blocks;
};
struct MegaArgs { GDesc d[4]; int nd; };

__global__ __launch_bounds__(256) void mega_gemm(MegaArgs args)
{
  constexpr int KS = 136;
  __shared__ ushort_t As[128*KS];
  __shared__ ushort_t Bs[128*KS];
  int id = blockIdx.x;
  int di = 0;
  while (di < args.nd-1 && id >= args.d[di].blocks) { id -= args.d[di].blocks; ++di; }
  GDesc g = args.d[di];
  const int per = g.rbp * g.cb;
  const int sp = id / per, r = id % per;
  const int xcd = r & 7, s2 = r >> 3;
  const int y = xcd + 8*(s2 / g.cb), cbi = s2 % g.cb;
  const int bm = y*128, bn = cbi*128;
  if (bm >= g.M) return;
  const int tid = threadIdx.x, lane = tid & 63, w = tid >> 6;
  const int wm = w & 1, wn = w >> 1;
  const int lr = lane & 15, lkq = lane >> 4;
  const int kbase = g.kOff + sp * g.K;
  const int hK = g.K >> 1;

  for (int f = tid; f < 128*hK; f += 256) {
    int row = f / hK, j2 = (f % hK)*2;
    int gm = bm + row;
    float2 va = make_float2(0.f,0.f);
    if (gm < g.M && kbase + j2 + 2 <= g.kMax)
      va = *reinterpret_cast<const float2*>(g.A + (long)gm*g.lda + kbase + j2);
    *reinterpret_cast<unsigned*>(&As[row*KS + j2]) = (unsigned)f2b(va.x) | ((unsigned)f2b(va.y)<<16);
    float2 vb = *reinterpret_cast<const float2*>(g.B + ((long)sp*g.Npad + bn + row)*g.K + j2);
    *reinterpret_cast<unsigned*>(&Bs[row*KS + j2]) = (unsigned)f2b(vb.x) | ((unsigned)f2b(vb.y)<<16);
  }
  const int padw = (128 - g.K) >> 1;
  for (int f = tid; f < 128*padw; f += 256) {
    int row = f / padw, jd = f % padw;
    *reinterpret_cast<unsigned*>(&As[row*KS + g.K + jd*2]) = 0u;
    *reinterpret_cast<unsigned*>(&Bs[row*KS + g.K + jd*2]) = 0u;
  }
  __syncthreads();

  f32x4 acc[4][4];
  #pragma unroll
  for (int i = 0; i < 4; ++i)
    #pragma unroll
    for (int j = 0; j < 4; ++j) acc[i][j] = f32x4{0.f,0.f,0.f,0.f};
  #pragma unroll
  for (int ks = 0; ks < 4; ++ks) {
    const int ko = ks*32 + lkq*8;
    bf16x8 af[4], bf[4];
    #pragma unroll
    for (int i = 0; i < 4; ++i)
      af[i] = *reinterpret_cast<const bf16x8*>(&As[(wm*64 + i*16 + lr)*KS + ko]);
    #pragma unroll
    for (int j = 0; j < 4; ++j)
      bf[j] = *reinterpret_cast<const bf16x8*>(&Bs[(wn*64 + j*16 + lr)*KS + ko]);
    #pragma unroll
    for (int i = 0; i < 4; ++i)
      #pragma unroll
      for (int j = 0; j < 4; ++j)
        acc[i][j] = __builtin_amdgcn_mfma_f32_16x16x32_bf16(af[i], bf[j], acc[i][j], 0, 0, 0);
  }
  #pragma unroll
  for (int i = 0; i < 4; ++i) {
    #pragma unroll
    for (int j = 0; j < 4; ++j) {
      #pragma unroll
      for (int rr = 0; rr < 4; ++rr) {
        int gr = bm + wm*64 + i*16 + lkq*4 + rr;
        int gc = bn + wn*64 + j*16 + lr;
        if (gr < g.M) {
          if (g.Cb) g.Cb[(long)gr * g.ldc + gc] = f2b(acc[i][j][rr]);
          else      g.Cf[((long)sp*g.M + gr)*g.ldc + gc] = acc[i][j][rr];
        }
      }
    }
  }
}

// ---------------- single pack kernel: Bn | Bp | XB2(+bias_x) | bertB | P2B | wattn | WfcT ----------------
constexpr long PK_E0 = (long)NODE_W*100;            // Bn
constexpr long PK_E1 = PK_E0 + (long)PATH_W*100;    // Bp
constexpr long PK_E2 = PK_E1 + 2L*XR_W*100;         // XB2
constexpr long PK_E3 = PK_E2 + 6L*128*128;          // bertB
constexpr long PK_E4 = PK_E3 + 10L*512*96;          // P2B
constexpr long PK_E5 = PK_E4 + 512;                 // wattn
constexpr long PK_E6 = PK_E5 + 378L*100;            // WfcT

__global__ void pack_all(
    const float* __restrict__ Wna, const float* __restrict__ Wia,
    const float* __restrict__ bna, const float* __restrict__ bia,
    const float* __restrict__ Wb, const float* __restrict__ Wih,
    const float* __restrict__ Wattn, const float* __restrict__ Wfc,
    float* __restrict__ Bn, float* __restrict__ Bp,
    float* __restrict__ XB2, float* __restrict__ bias_x,
    float* __restrict__ BertB, float* __restrict__ P2B,
    ushort_t* __restrict__ WAB, float* __restrict__ WfcT)
{
  long i = (long)blockIdx.x*256 + threadIdx.x;
  if (i < PK_E0) {
    int n = (int)(i / 100), k = (int)(i % 100);
    float v = 0.f;
    if (n < 500)                      v = Wna[(long)n*500 + k];
    else if (n >= 512 && n < 1012)    v = Wna[(long)(n-512)*500 + 100 + k];
    else if (n >= 1024 && n < 1124)   v = (k == n-1024) ? 1.f : 0.f;
    else if (n >= 1136 && n < 1236)   v = Wia[(long)(n-1136)*500 + k];
    else if (n >= 1280 && n < 1380)   v = (k == n-1280) ? 1.f : 0.f;
    else if (n >= 1392 && n < 1492)   v = Wia[(long)(n-1392)*500 + 100 + k];
    Bn[i] = v;
  } else if (i < PK_E1) {
    long j = i - PK_E0;
    int n = (int)(j / 100), k = (int)(j % 100);
    float v = 0.f;
    if (n < 500)                    v = Wna[(long)n*500 + 200 + k];
    else if (n >= 512 && n < 612)   v = (k == n-512) ? 1.f : 0.f;
    else if (n >= 624 && n < 724)   v = Wia[(long)(n-624)*500 + 200 + k];
    Bp[j] = v;
  } else if (i < PK_E2) {
    long j = i - PK_E1;
    if (j < XR_W) {
      float b = 0.f;
      if (j < 500) b = bna[j];
      else if (j >= 512 && j < 612) b = bia[j-512];
      bias_x[j] = b;
    }
    int s = (int)(j / (XR_W*100)), n = (int)((j / 100) % XR_W), k = (int)(j % 100);
    int k2 = s*100 + k;
    float v = 0.f;
    if (n < 500)                  v = Wna[(long)n*500 + 300 + k2];
    else if (n >= 512 && n < 612) v = Wia[(long)(n-512)*500 + 300 + k2];
    XB2[j] = v;
  } else if (i < PK_E3) {
    long j = i - PK_E2;
    int s = (int)(j / (128*128)), n = (int)((j / 128) % 128), k = (int)(j % 128);
    BertB[j] = (n < 100) ? Wb[(long)n*768 + s*128 + k] : 0.f;
  } else if (i < PK_E4) {
    long j = i - PK_E3;
    int s = (int)(j / (512*96)), n = (int)((j / 96) % 512), k = (int)(j % 96);
    int kg = s*96 + k;
    P2B[j] = (kg < 950) ? Wih[(long)n*950 + kg] : 0.f;
  } else if (i < PK_E5) {
    long j = i - PK_E4;
    WAB[j] = (j < 500) ? f2b(Wattn[j]) : (ushort_t)0;
  } else if (i < PK_E6) {
    long j = i - PK_E5;
    int o = (int)(j / 378), q = (int)(j % 378);
    WfcT[q*100 + o] = Wfc[j];
  }
}

// ---------------- reduce1: XR (2 splits + bias -> bf16) and bert (6 splits + bias -> rnn f32) ----------------
__global__ __launch_bounds__(256) void reduce1(
    const float* __restrict__ xrP, const float* __restrict__ bias_x, ushort_t* __restrict__ XR,
    const float* __restrict__ bertP, const float* __restrict__ bb, float* __restrict__ rnn)
{
  int bt = blockIdx.x, tid = threadIdx.x;
  for (int c = tid; c < XR_W; c += 256) {
    float v = xrP[(long)bt*XR_W + c] + xrP[((long)NBT + bt)*XR_W + c] + bias_x[c];
    XR[(long)bt*XR_W + c] = f2b(v);
  }
  if (tid < 100) {
    float v = bb[tid];
    #pragma unroll
    for (int s = 0; s < 6; ++s) v += bertP[((long)s*NBT + bt)*128 + tid];
    rnn[(long)bt*950 + 850 + tid] = v;
  }
}

// ---------------- reduce_p2: 10 splits + biases -> P2 fragment-layout bf16 ----------------
__global__ __launch_bounds__(512) void reduce_p2(
    const float* __restrict__ p2P, const float* __restrict__ bih, const float* __restrict__ bhh,
    ushort_t* __restrict__ P2)
{
  int bt = blockIdx.x, g = threadIdx.x;
  float v = bih[g] + bhh[g];
  #pragma unroll
  for (int s = 0; s < 10; ++s) v += p2P[((long)s*NBT + bt)*512 + g];
  int bq = bt / CT, tt = bt % CT;
  int q = g >> 7, rem = g & 127, ww = rem >> 4, lr2 = rem & 15;
  int lk2 = bq >> 2, rr = bq & 3;
  P2[((((long)tt*4 + q)*8 + ww)*4 + lk2)*64 + lr2*4 + rr] = f2b(v);
}

// ---------------- cw: per (b,t), all m: Wattn . tanh(T0A[a]+T0C[c]+TPP[p]+R) ----------------
__global__ __launch_bounds__(256) void cw2_kernel(
    const float* __restrict__ x, const ushort_t* __restrict__ NODE_ALL,
    const ushort_t* __restrict__ PATH_ALL, const ushort_t* __restrict__ XR,
    const ushort_t* __restrict__ WAB,
    const float* __restrict__ battn, float* __restrict__ cwT)
{
  int bt = blockIdx.x, b = bt / CT, t = bt % CT;
  int tid = threadIdx.x, w = tid >> 6, lane = tid & 63;
  __shared__ int idx_s[300];
  for (int i = tid; i < 300; i += 256) idx_s[i] = (int)x[(long)bt*XCH + 200 + i];
  float rseg[8], wseg[8];
  b8f(XR + (long)bt*XR_W + lane*8, rseg);
  b8f(WAB + lane*8, wseg);
  __syncthreads();
  float bat = battn[0];

  uint4 A0, C0, P0, A1, C1, P1;
  auto issue = [&](int m, uint4& A, uint4& C, uint4& P){
    if (m < CMCL) {
      int ai = idx_s[3*m], pi = idx_s[3*m+1], ci = idx_s[3*m+2];
      A = *reinterpret_cast<const uint4*>(NODE_ALL + (long)ai*NODE_W + lane*8);
      C = *reinterpret_cast<const uint4*>(NODE_ALL + (long)ci*NODE_W + 512 + lane*8);
      P = *reinterpret_cast<const uint4*>(PATH_ALL + (long)pi*PATH_W + lane*8);
    }
  };
  auto proc = [&](int m, const uint4& A, const uint4& C, const uint4& P){
    if (m >= CMCL) return;
    const unsigned ua[4] = {A.x, A.y, A.z, A.w};
    const unsigned uc[4] = {C.x, C.y, C.z, C.w};
    const unsigned up[4] = {P.x, P.y, P.z, P.w};
    float acc = 0.f;
    #pragma unroll
    for (int jj = 0; jj < 4; ++jj) {
      float lo = b2f(ua[jj] & 0xffffu) + b2f(uc[jj] & 0xffffu) + b2f(up[jj] & 0xffffu) + rseg[2*jj];
      float hi = b2f(ua[jj] >> 16)     + b2f(uc[jj] >> 16)     + b2f(up[jj] >> 16)     + rseg[2*jj+1];
      acc = fmaf(ftanh_(lo), wseg[2*jj], acc);
      acc = fmaf(ftanh_(hi), wseg[2*jj+1], acc);
    }
    acc = wredsum(acc);
    if (lane == 0) cwT[((long)b*CMCL + m)*CT + t] = acc + bat;
  };

  issue(w, A0, C0, P0);
  for (int it = 0; it < 25; it += 2) {
    int m0 = w + it*4;
    issue(m0 + 4, A1, C1, P1);
    proc(m0, A0, C0, P0);
    issue(m0 + 8, A0, C0, P0);
    proc(m0 + 4, A1, C1, P1);
  }
}

// ---------------- aw: softmax over t for each (b,m) ----------------
__global__ void aw_kernel(const float* __restrict__ cwT, float* __restrict__ awT)
{
  int bm = blockIdx.x; int lane = threadIdx.x;   // 64 threads
  const float* row = cwT + (long)bm * CT;
  bool h1 = lane < (CT - 64);
  float v0 = row[lane];
  float v1 = h1 ? row[64 + lane] : -3.0e38f;
  float mx = wredmax(fmaxf(v0, v1));
  float e0 = __expf(v0 - mx);
  float e1 = h1 ? __expf(v1 - mx) : 0.f;
  float s = wredsum(e0 + e1);
  float inv = frcp(s);
  awT[(long)bm*CT + lane] = e0 * inv;
  if (h1) awT[(long)bm*CT + 64 + lane] = e1 * inv;
}

// ---------------- fused: na + trans(LDS bf16) + kc-attention + w -> rnn[0:850], wbuf ----------------
__global__ __launch_bounds__(256) void fuse2_kernel(
    const float* __restrict__ x,
    const ushort_t* __restrict__ NODE_ALL, const ushort_t* __restrict__ PATH_ALL,
    const ushort_t* __restrict__ XR, const float* __restrict__ awT,
    const float* __restrict__ kc_emb, float* __restrict__ rnn,
    const float* __restrict__ Wt, const float* __restrict__ bt0, float* __restrict__ wbuf)
{
  int bt = blockIdx.x, b = bt / CT, t = bt % CT;
  int tid = threadIdx.x, w = tid >> 6, lane = tid & 63;
  int sub = lane >> 5, li = lane & 31;

  __shared__ ushort_t tr_s[100*TRS];
  __shared__ float nacc[4][344];
  __shared__ float ia_red[4][104];
  __shared__ float ia_f[100];
  __shared__ float aw_s[100];
  __shared__ int   idx_s[300];
  __shared__ float kcl[CKC];
  __shared__ int   act_k[CKC];
  __shared__ int   nact_s;
  __shared__ float kcn_s, awsum_s;

  for (int i = tid; i < 300; i += 256) idx_s[i] = (int)x[(long)bt*XCH + 200 + i];
  if (tid < 100) aw_s[tid] = awT[((long)b*CMCL + tid)*CT + t];
  if (tid < CKC) kcl[tid] = x[(long)bt*XCH + 1280 + tid];
  __syncthreads();
  if (tid == 0) {
    float kcn = 0.f; int na = 0;
    for (int k = 0; k < CKC; ++k) { float v = kcl[k]; kcn += v; if (v != 0.f) act_k[na++] = k; }
    nact_s = na; kcn_s = (kcn == 0.f) ? 1.f : kcn;
    float s = 0.f;
    for (int m = 0; m < CMCL; ++m) s += aw_s[m];
    awsum_s = s;
  }
  float rwseg[8];
  if (li >= 14 && li < 28) b8f(XR + (long)bt*XR_W + 512 + (li-14)*8, rwseg);
  __syncthreads();

  // ---- gather phase: full-wave aligned loads; segments [0,112)=emb, [112,224)=U, [224,256)=pad ----
  float na_a[8] = {}, na_c[8] = {}, na_p[8] = {};
  uint4 A0, C0, P0, A1, C1, P1;
  auto g_issue = [&](int m, uint4& A, uint4& C, uint4& P){
    if (m < CMCL) {
      int ai = idx_s[3*m], pi = idx_s[3*m+1], ci = idx_s[3*m+2];
      A = *reinterpret_cast<const uint4*>(NODE_ALL + (long)ai*NODE_W + 1024 + li*8);
      C = *reinterpret_cast<const uint4*>(NODE_ALL + (long)ci*NODE_W + 1280 + li*8);
      P = *reinterpret_cast<const uint4*>(PATH_ALL + (long)pi*PATH_W + 512  + li*8);
    }
  };
  auto g_proc = [&](int m, const uint4& A, const uint4& C, const uint4& P){
    if (m >= CMCL || li >= 28) return;
    const unsigned ua[4] = {A.x, A.y, A.z, A.w};
    const unsigned uc[4] = {C.x, C.y, C.z, C.w};
    const unsigned up[4] = {P.x, P.y, P.z, P.w};
    if (li < 14) {
      float awm = aw_s[m];
      #pragma unroll
      for (int jj = 0; jj < 4; ++jj) {
        na_a[2*jj]   = fmaf(awm, b2f(ua[jj] & 0xffffu), na_a[2*jj]);
        na_a[2*jj+1] = fmaf(awm, b2f(ua[jj] >> 16),     na_a[2*jj+1]);
        na_c[2*jj]   = fmaf(awm, b2f(uc[jj] & 0xffffu), na_c[2*jj]);
        na_c[2*jj+1] = fmaf(awm, b2f(uc[jj] >> 16),     na_c[2*jj+1]);
        na_p[2*jj]   = fmaf(awm, b2f(up[jj] & 0xffffu), na_p[2*jj]);
        na_p[2*jj+1] = fmaf(awm, b2f(up[jj] >> 16),     na_p[2*jj+1]);
      }
    } else {
      unsigned* d32 = reinterpret_cast<unsigned*>(&tr_s[m*TRS + (li-14)*8]);
      #pragma unroll
      for (int jj = 0; jj < 4; ++jj) {
        float lo = b2f(ua[jj] & 0xffffu) + b2f(uc[jj] & 0xffffu) + b2f(up[jj] & 0xffffu) + rwseg[2*jj];
        float hi = b2f(ua[jj] >> 16)     + b2f(uc[jj] >> 16)     + b2f(up[jj] >> 16)     + rwseg[2*jj+1];
        d32[jj] = (unsigned)f2b(lo) | ((unsigned)f2b(hi) << 16);
      }
    }
  };
  const int mb = w*2 + sub;
  g_issue(mb, A0, C0, P0);
  for (int it = 0; it < 13; it += 2) {
    g_issue((it+1)*8 + mb, A1, C1, P1);
    g_proc(it*8 + mb, A0, C0, P0);
    g_issue((it+2)*8 + mb, A0, C0, P0);
    g_proc((it+1)*8 + mb, A1, C1, P1);
  }
  #pragma unroll
  for (int j = 0; j < 8; ++j) {
    na_a[j] += __shfl_xor(na_a[j], 32);
    na_c[j] += __shfl_xor(na_c[j], 32);
    na_p[j] += __shfl_xor(na_p[j], 32);
  }
  if (lane < 14) {
    #pragma unroll
    for (int j = 0; j < 8; ++j) {
      nacc[w][      lane*8 + j] = na_a[j];
      nacc[w][112 + lane*8 + j] = na_c[j];
      nacc[w][224 + lane*8 + j] = na_p[j];
    }
  }
  __syncthreads();

  for (int q = tid; q < 336; q += 256) {
    float v = nacc[0][q] + nacc[1][q] + nacc[2][q] + nacc[3][q];
    int seg = q / 112, col = q % 112;
    if (col < 100) rnn[(long)bt*950 + 350 + seg*100 + col] = v;
  }
  for (int q = tid; q < CDIN; q += 256) {
    float xv = x[(long)bt*XCH + q];
    rnn[(long)bt*950 + 50 + q] = xv;
    rnn[(long)bt*950 + 650 + q] = awsum_s * xv;
  }
  if (tid < CKC) rnn[(long)bt*950 + tid] = kcl[tid];

  // ---- kc attention ----
  float ia0 = 0.f, ia1 = 0.f;
  const bool vrow1 = lane < 36;
  const bool vpv   = lane < 50;
  const int nact = nact_s;
  const unsigned* tr32_0 = reinterpret_cast<const unsigned*>(&tr_s[lane*TRS]);
  const unsigned* tr32_1 = reinterpret_cast<const unsigned*>(&tr_s[(64+lane)*TRS]);
  const unsigned* tr32   = reinterpret_cast<const unsigned*>(tr_s);
  for (int ki = w; ki < nact; ki += 4) {
    int k = act_k[ki];
    float kck = kcl[k];
    const float* ke = kc_emb + (long)k*100;
    float s0 = 0.f, s1 = 0.f;
    #pragma unroll 5
    for (int dh = 0; dh < 50; ++dh) {
      float k0 = ke[2*dh], k1 = ke[2*dh+1];
      unsigned u0 = tr32_0[dh];
      s0 = fmaf(k0, b2f(u0 & 0xffffu), s0);
      s0 = fmaf(k1, b2f(u0 >> 16), s0);
      if (vrow1) {
        unsigned u1 = tr32_1[dh];
        s1 = fmaf(k0, b2f(u1 & 0xffffu), s1);
        s1 = fmaf(k1, b2f(u1 >> 16), s1);
      }
    }
    s0 *= kck; s1 *= kck;
    float mx = wredmax(fmaxf(s0, vrow1 ? s1 : -3.0e38f));
    float p0e = __expf(s0 - mx);
    float p1e = vrow1 ? __expf(s1 - mx) : 0.f;
    float sm = wredsum(p0e + p1e);
    float inv = kck * frcp(sm);
    p0e *= inv; p1e *= inv;
    #pragma unroll 4
    for (int m = 0; m < CMCL; ++m) {
      float pm = (m < 64) ? __shfl(p0e, m) : __shfl(p1e, m - 64);
      if (vpv) {
        unsigned u = tr32[m*57 + lane];
        ia0 = fmaf(pm, b2f(u & 0xffffu), ia0);
        ia1 = fmaf(pm, b2f(u >> 16), ia1);
      }
    }
  }
  if (vpv) { ia_red[w][2*lane] = ia0; ia_red[w][2*lane+1] = ia1; }
  __syncthreads();
  if (tid < 100) {
    float v = (ia_red[0][tid] + ia_red[1][tid] + ia_red[2][tid] + ia_red[3][tid]) * frcp(kcn_s);
    rnn[(long)bt*950 + 250 + tid] = v;
    ia_f[tid] = v;
  }
  __syncthreads();
  // ---- folded w: Wt . [bert_vec | kc | ia] + bt ----
  if (tid < 64) {
    float acc = 0.f;
    for (int i = tid; i < 250; i += 64) {
      float f;
      if (i < 100)      f = rnn[(long)bt*950 + 850 + i];
      else if (i < 150) f = kcl[i - 100];
      else              f = ia_f[i - 150];
      acc = fmaf(Wt[i], f, acc);
    }
    acc = wredsum(acc);
    if (tid == 0) wbuf[bt] = acc + bt0[0];
  }
}

// ---------------- LSTM via MFMA: 1 block, 16 batches, Whh frags in VGPRs, P2-layout pre ----------------
__global__ __launch_bounds__(512) void lstm_mfma2(
    const ushort_t* __restrict__ P2,
    const float* __restrict__ Whh,
    float* __restrict__ lstm_out)
{
  const int tid = threadIdx.x, lane = tid & 63, w = tid >> 6;
  const int lr = lane & 15, lkq = lane >> 4;
  __shared__ ushort_t H[2][16 * HSTR];
  {
    ushort_t* hp = &H[0][0];
    for (int i = tid; i < 2*16*HSTR; i += 512) hp[i] = 0;
  }

  bf16x8 bw0[4], bw1[4], bw2[4], bw3[4];
  #pragma unroll
  for (int kk = 0; kk < 4; ++kk) {
    short s[8];
    const float* wp0 = Whh + (long)(0*128 + w*16 + lr) * 128 + kk*32 + lkq*8;
    const float* wp1 = Whh + (long)(1*128 + w*16 + lr) * 128 + kk*32 + lkq*8;
    const float* wp2 = Whh + (long)(2*128 + w*16 + lr) * 128 + kk*32 + lkq*8;
    const float* wp3 = Whh + (long)(3*128 + w*16 + lr) * 128 + kk*32 + lkq*8;
    #pragma unroll
    for (int j = 0; j < 8; ++j) s[j] = (short)f2b(wp0[j]);
    bw0[kk] = bf16x8{s[0],s[1],s[2],s[3],s[4],s[5],s[6],s[7]};
    #pragma unroll
    for (int j = 0; j < 8; ++j) s[j] = (short)f2b(wp1[j]);
    bw1[kk] = bf16x8{s[0],s[1],s[2],s[3],s[4],s[5],s[6],s[7]};
    #pragma unroll
    for (int j = 0; j < 8; ++j) s[j] = (short)f2b(wp2[j]);
    bw2[kk] = bf16x8{s[0],s[1],s[2],s[3],s[4],s[5],s[6],s[7]};
    #pragma unroll
    for (int j = 0; j < 8; ++j) s[j] = (short)f2b(wp3[j]);
    bw3[kk] = bf16x8{s[0],s[1],s[2],s[3],s[4],s[5],s[6],s[7]};
  }

  auto pptr = [&](int t, int q){
    return reinterpret_cast<const uint2*>(P2 + (((((long)t*4 + q)*8 + w)*4 + lkq)*64 + lr*4));
  };
  uint2 pc0 = *pptr(0,0), pc1 = *pptr(0,1), pc2 = *pptr(0,2), pc3 = *pptr(0,3);
  uint2 pn0, pn1, pn2, pn3;
  f32x4 c = {0.f,0.f,0.f,0.f};
  __syncthreads();

  int pb = 0;
  for (int t = 0; t < CT; ++t) {
    if (t + 1 < CT) { pn0 = *pptr(t+1,0); pn1 = *pptr(t+1,1); pn2 = *pptr(t+1,2); pn3 = *pptr(t+1,3); }
    bf16x8 a[4];
    #pragma unroll
    for (int kk = 0; kk < 4; ++kk)
      a[kk] = *reinterpret_cast<const bf16x8*>(&H[pb][lr*HSTR + kk*32 + lkq*8]);
    f32x4 acc0 = f32x4{ b2f(pc0.x & 0xffffu), b2f(pc0.x >> 16), b2f(pc0.y & 0xffffu), b2f(pc0.y >> 16) };
    f32x4 acc1 = f32x4{ b2f(pc1.x & 0xffffu), b2f(pc1.x >> 16), b2f(pc1.y & 0xffffu), b2f(pc1.y >> 16) };
    f32x4 acc2 = f32x4{ b2f(pc2.x & 0xffffu), b2f(pc2.x >> 16), b2f(pc2.y & 0xffffu), b2f(pc2.y >> 16) };
    f32x4 acc3 = f32x4{ b2f(pc3.x & 0xffffu), b2f(pc3.x >> 16), b2f(pc3.y & 0xffffu), b2f(pc3.y >> 16) };
    #pragma unroll
    for (int kk = 0; kk < 4; ++kk) {
      acc0 = __builtin_amdgcn_mfma_f32_16x16x32_bf16(a[kk], bw0[kk], acc0, 0,0,0);
      acc1 = __builtin_amdgcn_mfma_f32_16x16x32_bf16(a[kk], bw1[kk], acc1, 0,0,0);
      acc2 = __builtin_amdgcn_mfma_f32_16x16x32_bf16(a[kk], bw2[kk], acc2, 0,0,0);
      acc3 = __builtin_amdgcn_mfma_f32_16x16x32_bf16(a[kk], bw3[kk], acc3, 0,0,0);
    }
    #pragma unroll
    for (int r = 0; r < 4; ++r) {
      float ig = fsigmoid(acc0[r]);
      float fg = fsigmoid(acc1[r]);
      float gg = ftanh_(acc2[r]);
      float og = fsigmoid(acc3[r]);
      c[r] = fg*c[r] + ig*gg;
      float h = og * ftanh_(c[r]);
      int row = lkq*4 + r;
      H[pb^1][row*HSTR + w*16 + lr] = f2b(h);
      lstm_out[((long)row*CT + t)*128 + w*16 + lr] = h;
    }
    __syncthreads();
    pb ^= 1;
    pc0 = pn0; pc1 = pn1; pc2 = pn2; pc3 = pn3;
  }
}

// ---------------- final: causal attention + attended + FC + sigmoid ----------------
__global__ __launch_bounds__(256) void final_kernel(
    const float* __restrict__ x, const float* __restrict__ wbuf,
    const float* __restrict__ lstm_out, const float* __restrict__ WfcT,
    const float* __restrict__ bfc, float* __restrict__ out)
{
  int bt = blockIdx.x; int b = bt / CT, i = bt % CT;
  int tid = threadIdx.x;
  __shared__ float p_s[CT];
  __shared__ float feat_s[384];
  if (tid < 64) {
    bool h1 = (64 + tid) < CT;
    float v0 = (tid <= i) ? wbuf[(long)b*CT + tid] : -3.0e38f;
    float v1 = (h1 && (64 + tid) <= i) ? wbuf[(long)b*CT + 64 + tid] : -3.0e38f;
    float mx = wredmax(fmaxf(v0, v1));
    float e0 = (tid <= i) ? __expf(v0 - mx) : 0.f;
    float e1 = (h1 && (64 + tid) <= i) ? __expf(v1 - mx) : 0.f;
    float s = wredsum(e0 + e1);
    float inv = frcp(s);
    p_s[tid] = e0 * inv;
    if (h1) p_s[64 + tid] = e1 * inv;
  }
  __syncthreads();
  if (tid < CHID) {
    float cur = 0.f;
    #pragma unroll 4
    for (int j = 0; j <= i; ++j) cur = fmaf(p_s[j], lstm_out[((long)b*CT + j)*CHID + tid], cur);
    float l = lstm_out[((long)b*CT + i)*CHID + tid];
    float att;
    if (i == 0) att = l;
    else { att = 0.5f * l; if (i <= CT - 2) att = fmaf(0.5f, cur, att); }
    feat_s[250 + tid] = att;
  }
  for (int q = tid; q < 250; q += 256)
    feat_s[q] = (q < 200) ? x[(long)bt*XCH + q] : x[(long)bt*XCH + 1280 + (q - 200)];
  __syncthreads();
  if (tid < 100) {
    float acc = bfc[tid];
    #pragma unroll 4
    for (int q = 0; q < 378; ++q) acc = fmaf(WfcT[q*100 + tid], feat_s[q], acc);
    out[(long)bt*100 + tid] = fsigmoid(acc);
  }
}

extern "C" void kernel_launch(void* const* d_in, const int* in_sizes, int n_in,
                              void* d_out, int out_size, void* d_ws, size_t ws_size,
                              hipStream_t stream) {
  (void)in_sizes; (void)n_in; (void)out_size; (void)ws_size;
  const float* x        = (const float*)d_in[0];
  const float* node_emb = (const float*)d_in[1];
  const float* path_emb = (const float*)d_in[2];
  const float* Wb       = (const float*)d_in[3];
  const float* bb       = (const float*)d_in[4];
  const float* Wna      = (const float*)d_in[5];
  const float* bna      = (const float*)d_in[6];
  const float* Wia      = (const float*)d_in[7];
  const float* bia      = (const float*)d_in[8];
  const float* Wattn    = (const float*)d_in[9];
  const float* battn    = (const float*)d_in[10];
  const float* kc_emb   = (const float*)d_in[11];
  const float* Wt       = (const float*)d_in[12];
  const float* bt0      = (const float*)d_in[13];
  const float* Wih      = (const float*)d_in[14];
  const float* Whh      = (const float*)d_in[15];
  const float* bih      = (const float*)d_in[16];
  const float* bhh      = (const float*)d_in[17];
  const float* Wfc      = (const float*)d_in[18];
  const float* bfc      = (const float*)d_in[19];
  float* out = (float*)d_out;

  char* cur = (char*)d_ws;
  auto alloc = [&](size_t bytes)->char* {
    char* p = cur; cur += (bytes + 255) & ~(size_t)255; return p;
  };
  ushort_t* NODE_ALL = (ushort_t*)alloc((size_t)NNODE*NODE_W*2);   // 30.7 MB
  ushort_t* PATH_ALL = (ushort_t*)alloc((size_t)NPATH*PATH_W*2);   // 30.7 MB
  ushort_t* XR   = (ushort_t*)alloc((size_t)NBT*XR_W*2);
  float* Bn     = (float*)alloc((size_t)NODE_W*100*4);
  float* Bp     = (float*)alloc((size_t)PATH_W*100*4);
  float* XB2    = (float*)alloc((size_t)2*XR_W*100*4);
  float* BertB  = (float*)alloc((size_t)6*128*128*4);
  float* P2B    = (float*)alloc((size_t)10*512*96*4);
  float* bias_x = (float*)alloc((size_t)XR_W*4);
  ushort_t* WAB = (ushort_t*)alloc(512*2);
  float* cwT  = (float*)alloc((size_t)NBT*100*4);
  float* awT  = (float*)alloc((size_t)NBT*100*4);
  float* rnn  = (float*)alloc((size_t)NBT*950*4);
  char*  uni  = alloc((size_t)10*NBT*512*4);
  float* xrP   = (float*)uni;
  float* bertP = (float*)(uni + (size_t)2*NBT*XR_W*4);
  float* p2P   = (float*)uni;
  ushort_t* P2 = (ushort_t*)alloc((size_t)NBT*512*2);
  float* lstm = (float*)alloc((size_t)NBT*128*4);
  float* wbuf = (float*)alloc((size_t)NBT*4);
  float* WfcT = (float*)alloc((size_t)378*100*4);

  // ---- single pack launch ----
  pack_all<<<(unsigned)((PK_E6 + 255)/256), 256, 0, stream>>>(
      Wna, Wia, bna, bia, Wb, Wih, Wattn, Wfc,
      Bn, Bp, XB2, bias_x, BertB, P2B, WAB, WfcT);

  // ---- MEGA1: node, path, bert (split-K 6), XR (split-K 2) ----
  {
    MegaArgs a{};
    a.nd = 4;
    a.d[0] = { node_emb, Bn, nullptr, NODE_ALL, 100, 0, 100, 100, NNODE, NODE_W, 80, 12, 1, NODE_W, 80*12 };
    a.d[1] = { path_emb, Bp, nullptr, PATH_ALL, 100, 0, 100, 100, NPATH, PATH_W, 160, 6, 1, PATH_W, 160*6 };
    a.d[2] = { x, BertB, bertP, nullptr, XCH, 500, 1268, 128, NBT, 128, 16, 1, 6, 128, 16*1*6 };
    a.d[3] = { x, XB2, xrP, nullptr, XCH, 0, 200, 100, NBT, XR_W, 16, 5, 2, XR_W, 16*5*2 };
    int total = a.d[0].blocks + a.d[1].blocks + a.d[2].blocks + a.d[3].blocks;
    mega_gemm<<<total, 256, 0, stream>>>(a);
  }
  reduce1<<<NBT, 256, 0, stream>>>(xrP, bias_x, XR, bertP, bb, rnn);

  cw2_kernel<<<NBT,256,0,stream>>>(x, NODE_ALL, PATH_ALL, XR, WAB, battn, cwT);
  aw_kernel<<<CB*CMCL,64,0,stream>>>(cwT, awT);
  fuse2_kernel<<<NBT,256,0,stream>>>(x, NODE_ALL, PATH_ALL, XR, awT, kc_emb, rnn, Wt, bt0, wbuf);

  // ---- MEGA2: P2 pre-activation GEMM (split-K 10) + reduce into fragment layout ----
  {
    MegaArgs a{};
    a.nd = 1;
    a.d[0] = { rnn, P2B, p2P, nullptr, 950, 0, 950, 96, NBT, 512, 16, 4, 10, 512, 16*4*10 };
    mega_gemm<<<a.d[0].blocks, 256, 0, stream>>>(a);
  }
  reduce_p2<<<NBT, 512, 0, stream>>>(p2P, bih, bhh, P2);

  lstm_mfma2<<<1,512,0,stream>>>(P2, Whh, lstm);
  final_kernel<<<NBT,256,0,stream>>>(x, wbuf, lstm, WfcT, bfc, out);
}